// Round 2
// baseline (7600.004 us; speedup 1.0000x reference)
//
#include <hip/hip_runtime.h>
#include <hip/hip_fp16.h>

typedef _Float16 f16;
typedef _Float16 f16x8 __attribute__((ext_vector_type(8)));
typedef float f32x4 __attribute__((ext_vector_type(4)));

#define B_ 1024
#define T_ 128
#define F_ 9
#define H_ 256
#define P_ 2048

// ---------------- helpers ----------------
__device__ __forceinline__ float sigf(float x) { return 1.f / (1.f + __expf(-x)); }
__device__ __forceinline__ float tanh_(float x) {
  float a = fminf(fabsf(x), 12.f);
  float e = __expf(2.f * a);
  float r = 1.f - 2.f / (e + 1.f);
  return copysignf(r, x);
}

__device__ __forceinline__ float blk_sum(float v) {
  __shared__ float sh[8];
  int lane = threadIdx.x & 63, w = threadIdx.x >> 6;
  int nw = blockDim.x >> 6;
#pragma unroll
  for (int o = 32; o > 0; o >>= 1) v += __shfl_xor(v, o, 64);
  __syncthreads();
  if (lane == 0) sh[w] = v;
  __syncthreads();
  float t = 0.f;
  for (int i = 0; i < nw; i++) t += sh[i];
  return t;
}

// ---------------- generic fp16 MFMA GEMM ----------------
// C[M,N] = A[M,K] @ Bt[N,K]^T + bias ; M%128==0, N%128==0, K%32==0
__global__ __launch_bounds__(256) void gemm_f16(
    const f16* __restrict__ A, int lda,
    const f16* __restrict__ Bt, int ldb,
    const float* __restrict__ bias,
    f16* __restrict__ o16, int ldo16,
    float* __restrict__ o32, int ldo32,
    int M, int N, int K)
{
  __shared__ __align__(16) f16 As[128][40];
  __shared__ __align__(16) f16 Bs[128][40];
  const int tid = threadIdx.x;
  const int lane = tid & 63, wave = tid >> 6;
  const int wr = (wave >> 1) * 64, wc = (wave & 1) * 64;
  const int q = lane >> 4, l15 = lane & 15;
  const int bm = blockIdx.x * 128, bn = blockIdx.y * 128;

  f32x4 acc[4][4];
#pragma unroll
  for (int i = 0; i < 4; i++)
#pragma unroll
    for (int j = 0; j < 4; j++) acc[i][j] = (f32x4){0.f, 0.f, 0.f, 0.f};

  for (int k0 = 0; k0 < K; k0 += 32) {
#pragma unroll
    for (int c = 0; c < 2; ++c) {
      int ch = tid + c * 256;
      int row = ch >> 2, kh = (ch & 3) * 8;
      *(f16x8*)&As[row][kh] = *(const f16x8*)&A[(size_t)(bm + row) * lda + k0 + kh];
      *(f16x8*)&Bs[row][kh] = *(const f16x8*)&Bt[(size_t)(bn + row) * ldb + k0 + kh];
    }
    __syncthreads();
    f16x8 af[4], bf[4];
#pragma unroll
    for (int tm = 0; tm < 4; tm++) af[tm] = *(const f16x8*)&As[wr + tm * 16 + l15][q * 8];
#pragma unroll
    for (int tn = 0; tn < 4; tn++) bf[tn] = *(const f16x8*)&Bs[wc + tn * 16 + l15][q * 8];
#pragma unroll
    for (int tm = 0; tm < 4; tm++)
#pragma unroll
      for (int tn = 0; tn < 4; tn++)
        acc[tm][tn] = __builtin_amdgcn_mfma_f32_16x16x32_f16(af[tm], bf[tn], acc[tm][tn], 0, 0, 0);
    __syncthreads();
  }
#pragma unroll
  for (int tm = 0; tm < 4; tm++) {
#pragma unroll
    for (int tn = 0; tn < 4; tn++) {
      int colg = bn + wc + tn * 16 + l15;
      float bv = bias ? bias[colg] : 0.f;
#pragma unroll
      for (int r = 0; r < 4; r++) {
        int rowg = bm + wr + tm * 16 + q * 4 + r;
        float v = acc[tm][tn][r] + bv;
        if (o32) o32[(size_t)rowg * ldo32 + colg] = v;
        if (o16) o16[(size_t)rowg * ldo16 + colg] = (f16)v;
      }
    }
  }
}

// ---------------- fused LSTM: input-proj + recurrence, in place ----------------
// 64 blocks x 512 threads (8 waves), 16 batch rows/block.
// hio (B,T,256) f16: at step t rows are the layer input; overwritten with h_t.
// Wcat (1024,512) f16: [Wih | Whh] row-major. bias = bih+bhh (1024 f32).
// Per step: A = [x_t | h_{t-1}] (16x512, LDS), B-frags streamed from L2.
__global__ __launch_bounds__(512) void lstm_fused(
    f16* __restrict__ hio,
    const f16* __restrict__ Wcat,
    const float* __restrict__ bias)
{
  __shared__ __align__(16) f16 a_s[16][520];   // cols 0..255 x_t, 256..511 h
  const int tid = threadIdx.x;
  const int lane = tid & 63, wave = tid >> 6;
  const int q = lane >> 4, l15 = lane & 15;
  const int m0 = blockIdx.x * 16;

  for (int i = tid; i < 16 * 520; i += 512) (&a_s[0][0])[i] = (f16)0.f;  // h0 = 0

  float c[2][4];
#pragma unroll
  for (int a = 0; a < 2; a++)
#pragma unroll
    for (int r = 0; r < 4; r++) c[a][r] = 0.f;

  float bv[4][2];
#pragma unroll
  for (int g = 0; g < 4; g++)
#pragma unroll
    for (int ct = 0; ct < 2; ct++)
      bv[g][ct] = bias[g * 256 + wave * 32 + ct * 16 + l15];
  __syncthreads();

  for (int t = 0; t < T_; ++t) {
    { // stage x_t: 16 rows x 256 f16 = 512 x 16B chunks, 1/thread
      int row = tid >> 5, cc = (tid & 31) * 8;
      *(f16x8*)&a_s[row][cc] = *(const f16x8*)&hio[((size_t)(m0 + row) * T_ + t) * 256 + cc];
    }
    __syncthreads();   // S1: x staged, h(t-1) visible

    f16x8 af[16];
#pragma unroll
    for (int k = 0; k < 16; k++) af[k] = *(const f16x8*)&a_s[l15][k * 32 + q * 8];

    f32x4 acc[4][2];
#pragma unroll
    for (int g = 0; g < 4; ++g) {
#pragma unroll
      for (int ct = 0; ct < 2; ++ct) {
        f32x4 a = (f32x4){0.f, 0.f, 0.f, 0.f};
        const f16* wrow = Wcat + (size_t)(g * 256 + wave * 32 + ct * 16 + l15) * 512 + q * 8;
#pragma unroll
        for (int k = 0; k < 16; k++) {
          f16x8 bf = *(const f16x8*)&wrow[k * 32];  // B-frag straight from L2
          a = __builtin_amdgcn_mfma_f32_16x16x32_f16(af[k], bf, a, 0, 0, 0);
        }
        acc[g][ct] = a;
      }
    }

    f16 hnew[2][4];
#pragma unroll
    for (int ct = 0; ct < 2; ++ct) {
#pragma unroll
      for (int r = 0; r < 4; r++) {
        float ip = acc[0][ct][r] + bv[0][ct];
        float fp = acc[1][ct][r] + bv[1][ct];
        float gp = acc[2][ct][r] + bv[2][ct];
        float op = acc[3][ct][r] + bv[3][ct];
        float cn = sigf(fp) * c[ct][r] + sigf(ip) * tanh_(gp);
        c[ct][r] = cn;
        hnew[ct][r] = (f16)(sigf(op) * tanh_(cn));
      }
    }
    __syncthreads();   // S2: all waves done reading a_s for step t
#pragma unroll
    for (int ct = 0; ct < 2; ++ct) {
      int col = wave * 32 + ct * 16 + l15;
#pragma unroll
      for (int r = 0; r < 4; r++) {
        int row = q * 4 + r;
        a_s[row][256 + col] = hnew[ct][r];
        hio[((size_t)(m0 + row) * T_ + t) * 256 + col] = hnew[ct][r];
      }
    }
    // next iteration's S1 orders these writes before the af reads
  }
}

// ---------------- VSN ----------------
__global__ __launch_bounds__(256) void vsn_kernel(
    const float* __restrict__ x, const float* __restrict__ selw,
    const float* __restrict__ selb, const float* __restrict__ embw,
    const float* __restrict__ embb, f16* __restrict__ hout)
{
  size_t pos = blockIdx.x;
  const float* xr = x + pos * F_;
  float xv[F_];
#pragma unroll
  for (int f = 0; f < F_; f++) xv[f] = xr[f];
  float wv[F_]; float mx = -1e30f;
#pragma unroll
  for (int f = 0; f < F_; f++) {
    float s = selb[f];
#pragma unroll
    for (int f2 = 0; f2 < F_; f2++) s += xv[f2] * selw[f * F_ + f2];
    wv[f] = s; mx = fmaxf(mx, s);
  }
  float se = 0.f;
#pragma unroll
  for (int f = 0; f < F_; f++) { wv[f] = __expf(wv[f] - mx); se += wv[f]; }
  float inv = 1.f / se;
  int j = threadIdx.x;
  float hv = 0.f;
#pragma unroll
  for (int f = 0; f < F_; f++) hv += wv[f] * (xv[f] * embw[f * H_ + j] + embb[f * H_ + j]);
  hout[pos * H_ + j] = (f16)(hv * inv);
}

// ---------------- attention in h-space ----------------
// qk[b,h,:] = (W_k,h^T q_h) / 8 ; k-bias is constant over t -> cancels in softmax
__global__ __launch_bounds__(256) void qk_kernel(
    const float* __restrict__ qbuf, const float* __restrict__ attn_in_w,
    float* __restrict__ qk)
{
  __shared__ float qs[256];
  int b = blockIdx.x, j = threadIdx.x;
  qs[j] = qbuf[(size_t)b * 256 + j];
  __syncthreads();
#pragma unroll
  for (int h = 0; h < 4; h++) {
    float acc = 0.f;
    for (int d = 0; d < 64; d++)
      acc += qs[h * 64 + d] * attn_in_w[(size_t)(256 + h * 64 + d) * 256 + j];
    qk[((size_t)b * 4 + h) * 256 + j] = acc * 0.125f;  // 1/sqrt(64)
  }
}

// score[h,t] = qk[h]·h[b,t]; softmax over t; hbar[h] = sum_t p[h,t] h[b,t]
__global__ __launch_bounds__(256) void attnpool_kernel(
    const f16* __restrict__ hseq, const float* __restrict__ qk,
    float* __restrict__ hbar)
{
  __shared__ __align__(16) f16 hs[T_][264];  // +8 pad: spread row-major reads over banks
  __shared__ float qks[4][256];
  __shared__ float ps[4][T_];
  int b = blockIdx.x, tid = threadIdx.x;
  for (int i = tid; i < T_ * 32; i += 256) {
    int row = i >> 5, cc = (i & 31) * 8;
    *(f16x8*)&hs[row][cc] = *(const f16x8*)&hseq[((size_t)b * T_ + row) * 256 + cc];
  }
  for (int i = tid; i < 1024; i += 256) qks[i >> 8][i & 255] = qk[(size_t)b * 1024 + i];
  __syncthreads();
  if (tid < T_) {
    float s[4] = {0.f, 0.f, 0.f, 0.f};
    for (int cc = 0; cc < 32; cc++) {
      f16x8 v = *(const f16x8*)&hs[tid][cc * 8];
#pragma unroll
      for (int h = 0; h < 4; h++) {
        float a = 0.f;
#pragma unroll
        for (int j = 0; j < 8; j++) a += qks[h][cc * 8 + j] * (float)v[j];
        s[h] += a;
      }
    }
#pragma unroll
    for (int h = 0; h < 4; h++) ps[h][tid] = s[h];
  }
  __syncthreads();
  { // softmax: wave w handles head w (T=128 = 2 elems/lane)
    int w = tid >> 6, l = tid & 63;
    float a = ps[w][l], bb = ps[w][l + 64];
    float m = fmaxf(a, bb);
#pragma unroll
    for (int o = 32; o > 0; o >>= 1) m = fmaxf(m, __shfl_xor(m, o, 64));
    float e0 = __expf(a - m), e1 = __expf(bb - m);
    float se = e0 + e1;
#pragma unroll
    for (int o = 32; o > 0; o >>= 1) se += __shfl_xor(se, o, 64);
    float inv = 1.f / se;
    ps[w][l] = e0 * inv; ps[w][l + 64] = e1 * inv;
  }
  __syncthreads();
  int j = tid;
  float acc[4] = {0.f, 0.f, 0.f, 0.f};
  for (int t = 0; t < T_; t++) {
    float hv = (float)hs[t][j];
#pragma unroll
    for (int h = 0; h < 4; h++) acc[h] += ps[h][t] * hv;
  }
#pragma unroll
  for (int h = 0; h < 4; h++) hbar[((size_t)b * 4 + h) * 256 + j] = acc[h];
}

// o[b,d] = W_v[d,:]·hbar[b,h(d),:] + b_v[d]   (v folded through the pooled h)
__global__ __launch_bounds__(256) void vproj_kernel(
    const float* __restrict__ hbar, const float* __restrict__ attn_in_w,
    const float* __restrict__ attn_in_b, f16* __restrict__ aob)
{
  __shared__ float hb[4][256];
  int b = blockIdx.x, tid = threadIdx.x;
  for (int i = tid; i < 1024; i += 256) hb[i >> 8][i & 255] = hbar[(size_t)b * 1024 + i];
  __syncthreads();
  int d = tid, h = d >> 6;
  const float4* wr = (const float4*)(attn_in_w + (size_t)(512 + d) * 256);
  float acc = 0.f;
  for (int cc = 0; cc < 64; cc++) {
    float4 w4 = wr[cc];
    acc += w4.x * hb[h][cc * 4] + w4.y * hb[h][cc * 4 + 1]
         + w4.z * hb[h][cc * 4 + 2] + w4.w * hb[h][cc * 4 + 3];
  }
  aob[(size_t)b * 256 + d] = (f16)(acc + attn_in_b[512 + d]);
}

// ---------------- GNN prep ----------------
__global__ __launch_bounds__(256) void deg_adjn_kernel(
    const float* __restrict__ adj, const int* __restrict__ sku,
    f16* __restrict__ adjn)
{
  int bp = blockIdx.x;
  int p = sku[bp];
  int tid = threadIdx.x;
  float s = 0.f;
  for (int j = tid; j < P_; j += 256) s += adj[(size_t)p * P_ + j];
  float tot = blk_sum(s);
  float inv = 1.f / fmaxf(tot, 1e-6f);
  for (int b = tid; b < B_; b += 256)
    adjn[(size_t)bp * B_ + b] = (f16)(adj[(size_t)p * P_ + sku[b]] * inv);
}

__global__ void transpose_kernel(const float* __restrict__ hid, f16* __restrict__ hT)
{
  int i = blockIdx.x * 256 + threadIdx.x;
  int b = i >> 8, j = i & 255;
  hT[(size_t)j * B_ + b] = (f16)hid[i];
}

__global__ __launch_bounds__(256) void gelu_ln_kernel(
    const float* __restrict__ pre, const float* __restrict__ lg,
    const float* __restrict__ lb, float* __restrict__ enr,
    f16* __restrict__ hidcat)
{
  int row = blockIdx.x, j = threadIdx.x;
  float xv = pre[row * 256 + j];
  float ge = 0.5f * xv * (1.f + erff(xv * 0.70710678118654752f));
  float mu = blk_sum(ge) * (1.f / 256.f);
  float d = ge - mu;
  float var = blk_sum(d * d) * (1.f / 256.f);
  float y = d * rsqrtf(var + 1e-5f) * lg[j] + lb[j];
  enr[row * 256 + j] = y;
  hidcat[row * 512 + 256 + j] = (f16)y;
}

__global__ __launch_bounds__(256) void final_kernel(
    const float* __restrict__ gpre, const float* __restrict__ enr,
    const float* __restrict__ hid, const float* __restrict__ outw,
    const float* __restrict__ outb, float* __restrict__ out)
{
  int b = blockIdx.x, j = threadIdx.x;
  float gt = sigf(gpre[b * 256 + j]);
  float comb = gt * enr[b * 256 + j] + (1.f - gt) * hid[b * 256 + j];
  float v = comb * outw[j];
  float s = blk_sum(v);
  if (j == 0) out[b] = s + outb[0];
}

// ---------------- one-shot weight prep ----------------
__global__ void prep_kernel(
    const float* Wih0, const float* Whh0, const float* Wih1, const float* Whh1,
    const float* bih0, const float* bhh0, const float* bih1, const float* bhh1,
    const float* attn_in_w, const float* attn_out_w, const float* gnn_w,
    const float* gate_w,
    f16* wcat0, f16* wcat1, f16* attninf, f16* attnoutf, f16* gnnwf, f16* gatewf,
    float* bias0, float* bias1)
{
  int idx = blockIdx.x * 256 + threadIdx.x;
  if (idx < 524288) {
    int r = idx >> 9, c = idx & 511;
    wcat0[idx] = (f16)(c < 256 ? Wih0[r * 256 + c] : Whh0[r * 256 + c - 256]);
    wcat1[idx] = (f16)(c < 256 ? Wih1[r * 256 + c] : Whh1[r * 256 + c - 256]);
    return;
  }
  int i = idx - 524288;
  if (i < 65536) { attninf[i] = (f16)attn_in_w[i]; return; }
  i -= 65536;
  if (i < 65536) { attnoutf[i] = (f16)attn_out_w[i]; return; }
  i -= 65536;
  if (i < 65536) { gnnwf[i] = (f16)gnn_w[i]; return; }
  i -= 65536;
  if (i < 131072) { gatewf[i] = (f16)gate_w[i]; return; }
  i -= 131072;
  if (i < 1024) { bias0[i] = bih0[i] + bhh0[i]; return; }
  i -= 1024;
  if (i < 1024) { bias1[i] = bih1[i] + bhh1[i]; return; }
}

// ---------------- launch ----------------
extern "C" void kernel_launch(void* const* d_in, const int* in_sizes, int n_in,
                              void* d_out, int out_size, void* d_ws, size_t ws_size,
                              hipStream_t stream)
{
  const float* x         = (const float*)d_in[0];
  const int*   sku       = (const int*)  d_in[1];
  const float* adj       = (const float*)d_in[2];
  const float* vsn_emb_w = (const float*)d_in[3];
  const float* vsn_emb_b = (const float*)d_in[4];
  const float* vsn_sel_w = (const float*)d_in[5];
  const float* vsn_sel_b = (const float*)d_in[6];
  const float* Wih0 = (const float*)d_in[7];
  const float* Whh0 = (const float*)d_in[8];
  const float* bih0 = (const float*)d_in[9];
  const float* bhh0 = (const float*)d_in[10];
  const float* Wih1 = (const float*)d_in[11];
  const float* Whh1 = (const float*)d_in[12];
  const float* bih1 = (const float*)d_in[13];
  const float* bhh1 = (const float*)d_in[14];
  const float* attn_in_w  = (const float*)d_in[15];
  const float* attn_in_b  = (const float*)d_in[16];
  const float* attn_out_w = (const float*)d_in[17];
  const float* attn_out_b = (const float*)d_in[18];
  const float* gnn_w  = (const float*)d_in[19];
  const float* gnn_b  = (const float*)d_in[20];
  const float* ln_g   = (const float*)d_in[21];
  const float* ln_b   = (const float*)d_in[22];
  const float* gate_w = (const float*)d_in[23];
  const float* gate_b = (const float*)d_in[24];
  const float* out_w  = (const float*)d_in[25];
  const float* out_b  = (const float*)d_in[26];
  (void)in_sizes; (void)n_in; (void)out_size; (void)ws_size;

  char* wsb = (char*)d_ws;
  size_t off = 0;
  auto alloc = [&](size_t bytes) -> void* {
    void* p = wsb + off;
    off += (bytes + 255) & ~(size_t)255;
    return p;
  };
  // total ~88 MB
  f16* hA      = (f16*)alloc((size_t)B_ * T_ * H_ * 2);   // 67 MB: vsn out -> lstm0 -> lstm1 (in place)
  f16* wcat0f  = (f16*)alloc((size_t)1024 * 512 * 2);
  f16* wcat1f  = (f16*)alloc((size_t)1024 * 512 * 2);
  f16* attninf = (f16*)alloc((size_t)256 * 256 * 2);      // q-rows only
  f16* attnoutf= (f16*)alloc((size_t)256 * 256 * 2);
  f16* gnnwf   = (f16*)alloc((size_t)256 * 256 * 2);
  f16* gatewf  = (f16*)alloc((size_t)256 * 512 * 2);
  float* bias0 = (float*)alloc(1024 * 4);
  float* bias1 = (float*)alloc(1024 * 4);
  float* qbuf  = (float*)alloc((size_t)B_ * 256 * 4);
  float* qk    = (float*)alloc((size_t)B_ * 4 * 256 * 4);
  float* hbar  = (float*)alloc((size_t)B_ * 4 * 256 * 4);
  f16* aob     = (f16*)alloc((size_t)B_ * 256 * 2);
  float* hidden32 = (float*)alloc((size_t)B_ * 256 * 4);
  f16* hidcat  = (f16*)alloc((size_t)B_ * 512 * 2);
  f16* hT      = (f16*)alloc((size_t)256 * B_ * 2);
  f16* adjn    = (f16*)alloc((size_t)B_ * B_ * 2);
  f16* aggf    = (f16*)alloc((size_t)B_ * 256 * 2);
  float* gnnpre= (float*)alloc((size_t)B_ * 256 * 4);
  float* enr32 = (float*)alloc((size_t)B_ * 256 * 4);
  float* gatepre=(float*)alloc((size_t)B_ * 256 * 4);

  // weight prep (one kernel)
  prep_kernel<<<3336, 256, 0, stream>>>(
      Wih0, Whh0, Wih1, Whh1, bih0, bhh0, bih1, bhh1,
      attn_in_w, attn_out_w, gnn_w, gate_w,
      wcat0f, wcat1f, attninf, attnoutf, gnnwf, gatewf, bias0, bias1);

  // 1) VSN -> hA
  vsn_kernel<<<B_ * T_, 256, 0, stream>>>(x, vsn_sel_w, vsn_sel_b, vsn_emb_w, vsn_emb_b, hA);
  // 2) LSTM layers, fused input-proj, in place
  lstm_fused<<<64, 512, 0, stream>>>(hA, wcat0f, bias0);
  lstm_fused<<<64, 512, 0, stream>>>(hA, wcat1f, bias1);

  // 3) q at t=T-1 (with bias), f32
  dim3 gS(B_ / 128, 256 / 128);
  gemm_f16<<<gS, 256, 0, stream>>>(hA + (size_t)(T_ - 1) * 256, T_ * 256, attninf, 256,
                                   attn_in_b, nullptr, 0, qbuf, 256, B_, 256, 256);
  // 4) attention folded into h-space
  qk_kernel<<<B_, 256, 0, stream>>>(qbuf, attn_in_w, qk);
  attnpool_kernel<<<B_, 256, 0, stream>>>(hA, qk, hbar);
  vproj_kernel<<<B_, 256, 0, stream>>>(hbar, attn_in_w, attn_in_b, aob);
  // 5) hidden = aob @ attn_out^T + b
  gemm_f16<<<gS, 256, 0, stream>>>(aob, 256, attnoutf, 256, attn_out_b,
                                   hidcat, 512, hidden32, 256, B_, 256, 256);
  // 6) GNN (gathered: only sku rows/cols of adj matter)
  deg_adjn_kernel<<<B_, 256, 0, stream>>>(adj, sku, adjn);
  transpose_kernel<<<B_, 256, 0, stream>>>(hidden32, hT);
  gemm_f16<<<gS, 256, 0, stream>>>(adjn, 1024, hT, 1024, nullptr,
                                   aggf, 256, nullptr, 0, B_, 256, 1024);
  gemm_f16<<<gS, 256, 0, stream>>>(aggf, 256, gnnwf, 256, gnn_b,
                                   nullptr, 0, gnnpre, 256, B_, 256, 256);
  gelu_ln_kernel<<<B_, 256, 0, stream>>>(gnnpre, ln_g, ln_b, enr32, hidcat);
  // 7) gate + output
  gemm_f16<<<gS, 256, 0, stream>>>(hidcat, 512, gatewf, 512, gate_b,
                                   nullptr, 0, gatepre, 256, B_, 256, 512);
  final_kernel<<<B_, 256, 0, stream>>>(gatepre, enr32, hidden32, out_w, out_b, (float*)d_out);
}

// Round 4
// 7421.581 us; speedup vs baseline: 1.0240x; 1.0240x over previous
//
#include <hip/hip_runtime.h>
#include <hip/hip_fp16.h>

typedef _Float16 f16;
typedef _Float16 f16x8 __attribute__((ext_vector_type(8)));
typedef float f32x4 __attribute__((ext_vector_type(4)));

#define B_ 1024
#define T_ 128
#define F_ 9
#define H_ 256
#define P_ 2048

// ---------------- helpers ----------------
__device__ __forceinline__ float sigf(float x) { return 1.f / (1.f + __expf(-x)); }
__device__ __forceinline__ float tanh_(float x) {
  float a = fminf(fabsf(x), 12.f);
  float e = __expf(2.f * a);
  float r = 1.f - 2.f / (e + 1.f);
  return copysignf(r, x);
}

__device__ __forceinline__ float blk_sum(float v) {
  __shared__ float sh[8];
  int lane = threadIdx.x & 63, w = threadIdx.x >> 6;
  int nw = blockDim.x >> 6;
#pragma unroll
  for (int o = 32; o > 0; o >>= 1) v += __shfl_xor(v, o, 64);
  __syncthreads();
  if (lane == 0) sh[w] = v;
  __syncthreads();
  float t = 0.f;
  for (int i = 0; i < nw; i++) t += sh[i];
  return t;
}

// ---------------- generic fp16 MFMA GEMM ----------------
__global__ __launch_bounds__(256) void gemm_f16(
    const f16* __restrict__ A, int lda,
    const f16* __restrict__ Bt, int ldb,
    const float* __restrict__ bias,
    f16* __restrict__ o16, int ldo16,
    float* __restrict__ o32, int ldo32,
    int M, int N, int K)
{
  __shared__ __align__(16) f16 As[128][40];
  __shared__ __align__(16) f16 Bs[128][40];
  const int tid = threadIdx.x;
  const int lane = tid & 63, wave = tid >> 6;
  const int wr = (wave >> 1) * 64, wc = (wave & 1) * 64;
  const int q = lane >> 4, l15 = lane & 15;
  const int bm = blockIdx.x * 128, bn = blockIdx.y * 128;

  f32x4 acc[4][4];
#pragma unroll
  for (int i = 0; i < 4; i++)
#pragma unroll
    for (int j = 0; j < 4; j++) acc[i][j] = (f32x4){0.f, 0.f, 0.f, 0.f};

  for (int k0 = 0; k0 < K; k0 += 32) {
#pragma unroll
    for (int c = 0; c < 2; ++c) {
      int ch = tid + c * 256;
      int row = ch >> 2, kh = (ch & 3) * 8;
      *(f16x8*)&As[row][kh] = *(const f16x8*)&A[(size_t)(bm + row) * lda + k0 + kh];
      *(f16x8*)&Bs[row][kh] = *(const f16x8*)&Bt[(size_t)(bn + row) * ldb + k0 + kh];
    }
    __syncthreads();
    f16x8 af[4], bf[4];
#pragma unroll
    for (int tm = 0; tm < 4; tm++) af[tm] = *(const f16x8*)&As[wr + tm * 16 + l15][q * 8];
#pragma unroll
    for (int tn = 0; tn < 4; tn++) bf[tn] = *(const f16x8*)&Bs[wc + tn * 16 + l15][q * 8];
#pragma unroll
    for (int tm = 0; tm < 4; tm++)
#pragma unroll
      for (int tn = 0; tn < 4; tn++)
        acc[tm][tn] = __builtin_amdgcn_mfma_f32_16x16x32_f16(af[tm], bf[tn], acc[tm][tn], 0, 0, 0);
    __syncthreads();
  }
#pragma unroll
  for (int tm = 0; tm < 4; tm++) {
#pragma unroll
    for (int tn = 0; tn < 4; tn++) {
      int colg = bn + wc + tn * 16 + l15;
      float bv = bias ? bias[colg] : 0.f;
#pragma unroll
      for (int r = 0; r < 4; r++) {
        int rowg = bm + wr + tm * 16 + q * 4 + r;
        float v = acc[tm][tn][r] + bv;
        if (o32) o32[(size_t)rowg * ldo32 + colg] = v;
        if (o16) o16[(size_t)rowg * ldo16 + colg] = (f16)v;
      }
    }
  }
}

// ---------------- fused LSTM, packed-coalesced weights ----------------
// 64 blocks x 512 threads, 16 batch rows/block, in-place on hio (B,T,256).
// wpk: fragment-major packed [wave(8)][g(4)][ct(2)][k(16)][lane(64)][8 f16]
//   -> every weight load is 64 lanes x 16B = one contiguous 1KB transaction,
//      and the whole 1MB matrix stays L2-resident across the 128 steps.
// ap LDS: fragment-major A [k(16)][lane(64)+2pad][8] -> conflict-free b128.
__global__ __launch_bounds__(512) void lstm_fused(
    f16* __restrict__ hio,
    const f16* __restrict__ wpk,
    const float* __restrict__ bias)
{
  __shared__ __align__(16) f16 ap[16][66][8];
  const int tid = threadIdx.x;
  const int lane = tid & 63, wave = tid >> 6;
  const int q = lane >> 4, l15 = lane & 15;
  const int m0 = blockIdx.x * 16;

  for (int i = tid; i < 16 * 66 * 8; i += 512) (&ap[0][0][0])[i] = (f16)0.f;

  float c[2][4];
#pragma unroll
  for (int a = 0; a < 2; a++)
#pragma unroll
    for (int r = 0; r < 4; r++) c[a][r] = 0.f;

  float bv[4][2];
#pragma unroll
  for (int g = 0; g < 4; g++)
#pragma unroll
    for (int ct = 0; ct < 2; ct++)
      bv[g][ct] = bias[g * 256 + wave * 32 + ct * 16 + l15];

  // x staging: thread -> one 16B chunk. row=tid>>5, col0=(tid&31)*8
  const int sr = tid >> 5, sc0 = (tid & 31) * 8;
  const int sk = sc0 >> 5, sq = (sc0 >> 3) & 3;
  f16* sdst = &ap[sk][sq * 16 + sr][0];
  const f16* ssrc = &hio[((size_t)(m0 + sr) * T_) * 256 + sc0];
  __syncthreads();

  for (int t = 0; t < T_; ++t) {
    *(f16x8*)sdst = *(const f16x8*)(ssrc + (size_t)t * 256);
    __syncthreads();   // S1: x staged, h(t-1) frags visible

    f16x8 af[16];
#pragma unroll
    for (int k = 0; k < 16; k++) af[k] = *(const f16x8*)&ap[k][lane][0];

    f32x4 acc[4][2];
    const f16* wb0 = wpk + (size_t)wave * 65536 + (size_t)lane * 8;
#pragma unroll
    for (int g = 0; g < 4; ++g) {
#pragma unroll
      for (int ct = 0; ct < 2; ++ct) {
        f32x4 a = (f32x4){0.f, 0.f, 0.f, 0.f};
        const f16* wp = wb0 + g * 16384 + ct * 8192;
#pragma unroll
        for (int k = 0; k < 16; k++) {
          f16x8 bf = *(const f16x8*)(wp + k * 512);   // coalesced 1KB/wave
          a = __builtin_amdgcn_mfma_f32_16x16x32_f16(af[k], bf, a, 0, 0, 0);
        }
        acc[g][ct] = a;
      }
    }

    f16 hnew[2][4];
#pragma unroll
    for (int ct = 0; ct < 2; ++ct) {
#pragma unroll
      for (int r = 0; r < 4; r++) {
        float ip = acc[0][ct][r] + bv[0][ct];
        float fp = acc[1][ct][r] + bv[1][ct];
        float gp = acc[2][ct][r] + bv[2][ct];
        float op = acc[3][ct][r] + bv[3][ct];
        float cn = sigf(fp) * c[ct][r] + sigf(ip) * tanh_(gp);
        c[ct][r] = cn;
        hnew[ct][r] = (f16)(sigf(op) * tanh_(cn));
      }
    }
    __syncthreads();   // S2: all reads of step-t ap done
#pragma unroll
    for (int ct = 0; ct < 2; ++ct) {
      int col = wave * 32 + ct * 16 + l15;
      int kh = 8 + (col >> 5), qh = (col >> 3) & 3, jh = col & 7;
#pragma unroll
      for (int r = 0; r < 4; r++) {
        int row = q * 4 + r;
        ap[kh][qh * 16 + row][jh] = hnew[ct][r];
        hio[((size_t)(m0 + row) * T_ + t) * 256 + col] = hnew[ct][r];
      }
    }
  }
}

// ---------------- VSN, two-phase ----------------
// phase 1: per-position softmax weights -> wb[pos][0..8]=wts, [9..17]=wts*x
__global__ __launch_bounds__(256) void vsn_w_kernel(
    const float* __restrict__ x, const float* __restrict__ selw,
    const float* __restrict__ selb, float* __restrict__ wb)
{
  int pos = blockIdx.x * 256 + threadIdx.x;   // 512 blocks
  const float* xr = x + (size_t)pos * F_;
  float xv[F_];
#pragma unroll
  for (int f = 0; f < F_; f++) xv[f] = xr[f];
  float wv[F_]; float mx = -1e30f;
#pragma unroll
  for (int f = 0; f < F_; f++) {
    float s = selb[f];
#pragma unroll
    for (int f2 = 0; f2 < F_; f2++) s += xv[f2] * selw[f * F_ + f2];
    wv[f] = s; mx = fmaxf(mx, s);
  }
  float se = 0.f;
#pragma unroll
  for (int f = 0; f < F_; f++) { wv[f] = __expf(wv[f] - mx); se += wv[f]; }
  float inv = 1.f / se;
  float* o = wb + (size_t)pos * 18;
#pragma unroll
  for (int f = 0; f < F_; f++) {
    float wt = wv[f] * inv;
    o[f] = wt; o[9 + f] = wt * xv[f];
  }
}

// phase 2: h[pos][j] = sum_f wx[f]*embw[f][j] + wts[f]*embb[f][j]
__global__ __launch_bounds__(256) void vsn_h_kernel(
    const float* __restrict__ wb, const float* __restrict__ embw,
    const float* __restrict__ embb, f16* __restrict__ hout)
{
  int j = threadIdx.x;
  float ew[F_], eb[F_];
#pragma unroll
  for (int f = 0; f < F_; f++) { ew[f] = embw[f * H_ + j]; eb[f] = embb[f * H_ + j]; }
  for (int i = 0; i < 128; i++) {
    size_t pos = blockIdx.x + (size_t)i * 1024;
    const float* w = wb + pos * 18;
    float h = 0.f;
#pragma unroll
    for (int f = 0; f < F_; f++) h += w[9 + f] * ew[f] + w[f] * eb[f];
    hout[pos * H_ + j] = (f16)h;
  }
}

// ---------------- attention in h-space ----------------
__global__ __launch_bounds__(256) void qk_kernel(
    const float* __restrict__ qbuf, const float* __restrict__ attn_in_w,
    float* __restrict__ qk)
{
  __shared__ float qs[256];
  int b = blockIdx.x, j = threadIdx.x;
  qs[j] = qbuf[(size_t)b * 256 + j];
  __syncthreads();
#pragma unroll
  for (int h = 0; h < 4; h++) {
    float acc = 0.f;
    for (int d = 0; d < 64; d++)
      acc += qs[h * 64 + d] * attn_in_w[(size_t)(256 + h * 64 + d) * 256 + j];
    qk[((size_t)b * 4 + h) * 256 + j] = acc * 0.125f;
  }
}

__global__ __launch_bounds__(256) void attnpool_kernel(
    const f16* __restrict__ hseq, const float* __restrict__ qk,
    float* __restrict__ hbar)
{
  __shared__ __align__(16) f16 hs[T_][264];
  __shared__ float qks[4][256];
  __shared__ float ps[4][T_];
  int b = blockIdx.x, tid = threadIdx.x;
  for (int i = tid; i < T_ * 32; i += 256) {
    int row = i >> 5, cc = (i & 31) * 8;
    *(f16x8*)&hs[row][cc] = *(const f16x8*)&hseq[((size_t)b * T_ + row) * 256 + cc];
  }
  for (int i = tid; i < 1024; i += 256) qks[i >> 8][i & 255] = qk[(size_t)b * 1024 + i];
  __syncthreads();
  if (tid < T_) {
    float s[4] = {0.f, 0.f, 0.f, 0.f};
    for (int cc = 0; cc < 32; cc++) {
      f16x8 v = *(const f16x8*)&hs[tid][cc * 8];
#pragma unroll
      for (int h = 0; h < 4; h++) {
        float a = 0.f;
#pragma unroll
        for (int j = 0; j < 8; j++) a += qks[h][cc * 8 + j] * (float)v[j];
        s[h] += a;
      }
    }
#pragma unroll
    for (int h = 0; h < 4; h++) ps[h][tid] = s[h];
  }
  __syncthreads();
  {
    int w = tid >> 6, l = tid & 63;
    float a = ps[w][l], bb = ps[w][l + 64];
    float m = fmaxf(a, bb);
#pragma unroll
    for (int o = 32; o > 0; o >>= 1) m = fmaxf(m, __shfl_xor(m, o, 64));
    float e0 = __expf(a - m), e1 = __expf(bb - m);
    float se = e0 + e1;
#pragma unroll
    for (int o = 32; o > 0; o >>= 1) se += __shfl_xor(se, o, 64);
    float inv = 1.f / se;
    ps[w][l] = e0 * inv; ps[w][l + 64] = e1 * inv;
  }
  __syncthreads();
  int j = tid;
  float acc[4] = {0.f, 0.f, 0.f, 0.f};
  for (int t = 0; t < T_; t++) {
    float hv = (float)hs[t][j];
#pragma unroll
    for (int h = 0; h < 4; h++) acc[h] += ps[h][t] * hv;
  }
#pragma unroll
  for (int h = 0; h < 4; h++) hbar[((size_t)b * 4 + h) * 256 + j] = acc[h];
}

__global__ __launch_bounds__(256) void vproj_kernel(
    const float* __restrict__ hbar, const float* __restrict__ attn_in_w,
    const float* __restrict__ attn_in_b, f16* __restrict__ aob)
{
  __shared__ float hb[4][256];
  int b = blockIdx.x, tid = threadIdx.x;
  for (int i = tid; i < 1024; i += 256) hb[i >> 8][i & 255] = hbar[(size_t)b * 1024 + i];
  __syncthreads();
  int d = tid, h = d >> 6;
  const float4* wr = (const float4*)(attn_in_w + (size_t)(512 + d) * 256);
  float acc = 0.f;
  for (int cc = 0; cc < 64; cc++) {
    float4 w4 = wr[cc];
    acc += w4.x * hb[h][cc * 4] + w4.y * hb[h][cc * 4 + 1]
         + w4.z * hb[h][cc * 4 + 2] + w4.w * hb[h][cc * 4 + 3];
  }
  aob[(size_t)b * 256 + d] = (f16)(acc + attn_in_b[512 + d]);
}

// ---------------- GNN prep ----------------
__global__ __launch_bounds__(256) void deg_adjn_kernel(
    const float* __restrict__ adj, const int* __restrict__ sku,
    f16* __restrict__ adjn)
{
  int bp = blockIdx.x;
  int p = sku[bp];
  int tid = threadIdx.x;
  float s = 0.f;
  for (int j = tid; j < P_; j += 256) s += adj[(size_t)p * P_ + j];
  float tot = blk_sum(s);
  float inv = 1.f / fmaxf(tot, 1e-6f);
  for (int b = tid; b < B_; b += 256)
    adjn[(size_t)bp * B_ + b] = (f16)(adj[(size_t)p * P_ + sku[b]] * inv);
}

__global__ void transpose_kernel(const float* __restrict__ hid, f16* __restrict__ hT)
{
  int i = blockIdx.x * 256 + threadIdx.x;
  int b = i >> 8, j = i & 255;
  hT[(size_t)j * B_ + b] = (f16)hid[i];
}

__global__ __launch_bounds__(256) void gelu_ln_kernel(
    const float* __restrict__ pre, const float* __restrict__ lg,
    const float* __restrict__ lb, float* __restrict__ enr,
    f16* __restrict__ hidcat)
{
  int row = blockIdx.x, j = threadIdx.x;
  float xv = pre[row * 256 + j];
  float ge = 0.5f * xv * (1.f + erff(xv * 0.70710678118654752f));
  float mu = blk_sum(ge) * (1.f / 256.f);
  float d = ge - mu;
  float var = blk_sum(d * d) * (1.f / 256.f);
  float y = d * rsqrtf(var + 1e-5f) * lg[j] + lb[j];
  enr[row * 256 + j] = y;
  hidcat[row * 512 + 256 + j] = (f16)y;
}

__global__ __launch_bounds__(256) void final_kernel(
    const float* __restrict__ gpre, const float* __restrict__ enr,
    const float* __restrict__ hid, const float* __restrict__ outw,
    const float* __restrict__ outb, float* __restrict__ out)
{
  int b = blockIdx.x, j = threadIdx.x;
  float gt = sigf(gpre[b * 256 + j]);
  float comb = gt * enr[b * 256 + j] + (1.f - gt) * hid[b * 256 + j];
  float v = comb * outw[j];
  float s = blk_sum(v);
  if (j == 0) out[b] = s + outb[0];
}

// ---------------- one-shot weight prep ----------------
// wpk layout: elem = ((((w*4+g)*2+ct)*16+k)*64+lane)*8 + j
// row = g*256 + w*32 + ct*16 + (lane&15); col = k*32 + (lane>>4)*8 + j
// total threads needed: 524288 + 3*65536 + 131072 + 2*1024 = 854016 = 3336 blocks
__global__ void prep_kernel(
    const float* Wih0, const float* Whh0, const float* Wih1, const float* Whh1,
    const float* bih0, const float* bhh0, const float* bih1, const float* bhh1,
    const float* attn_in_w, const float* attn_out_w, const float* gnn_w,
    const float* gate_w,
    f16* wpk0, f16* wpk1, f16* attninf, f16* attnoutf, f16* gnnwf, f16* gatewf,
    float* bias0, float* bias1)
{
  int idx = blockIdx.x * 256 + threadIdx.x;
  if (idx < 524288) {
    int j = idx & 7, lane = (idx >> 3) & 63, k = (idx >> 9) & 15;
    int ct = (idx >> 13) & 1, g = (idx >> 14) & 3, w = (idx >> 16) & 7;
    int row = g * 256 + w * 32 + ct * 16 + (lane & 15);
    int col = k * 32 + (lane >> 4) * 8 + j;
    float v0 = col < 256 ? Wih0[(size_t)row * 256 + col] : Whh0[(size_t)row * 256 + col - 256];
    float v1 = col < 256 ? Wih1[(size_t)row * 256 + col] : Whh1[(size_t)row * 256 + col - 256];
    wpk0[idx] = (f16)v0;
    wpk1[idx] = (f16)v1;
    return;
  }
  int i = idx - 524288;
  if (i < 65536) { attninf[i] = (f16)attn_in_w[i]; return; }
  i -= 65536;
  if (i < 65536) { attnoutf[i] = (f16)attn_out_w[i]; return; }
  i -= 65536;
  if (i < 65536) { gnnwf[i] = (f16)gnn_w[i]; return; }
  i -= 65536;
  if (i < 131072) { gatewf[i] = (f16)gate_w[i]; return; }
  i -= 131072;
  if (i < 1024) { bias0[i] = bih0[i] + bhh0[i]; return; }
  i -= 1024;
  if (i < 1024) { bias1[i] = bih1[i] + bhh1[i]; return; }
}

// ---------------- launch ----------------
extern "C" void kernel_launch(void* const* d_in, const int* in_sizes, int n_in,
                              void* d_out, int out_size, void* d_ws, size_t ws_size,
                              hipStream_t stream)
{
  const float* x         = (const float*)d_in[0];
  const int*   sku       = (const int*)  d_in[1];
  const float* adj       = (const float*)d_in[2];
  const float* vsn_emb_w = (const float*)d_in[3];
  const float* vsn_emb_b = (const float*)d_in[4];
  const float* vsn_sel_w = (const float*)d_in[5];
  const float* vsn_sel_b = (const float*)d_in[6];
  const float* Wih0 = (const float*)d_in[7];
  const float* Whh0 = (const float*)d_in[8];
  const float* bih0 = (const float*)d_in[9];
  const float* bhh0 = (const float*)d_in[10];
  const float* Wih1 = (const float*)d_in[11];
  const float* Whh1 = (const float*)d_in[12];
  const float* bih1 = (const float*)d_in[13];
  const float* bhh1 = (const float*)d_in[14];
  const float* attn_in_w  = (const float*)d_in[15];
  const float* attn_in_b  = (const float*)d_in[16];
  const float* attn_out_w = (const float*)d_in[17];
  const float* attn_out_b = (const float*)d_in[18];
  const float* gnn_w  = (const float*)d_in[19];
  const float* gnn_b  = (const float*)d_in[20];
  const float* ln_g   = (const float*)d_in[21];
  const float* ln_b   = (const float*)d_in[22];
  const float* gate_w = (const float*)d_in[23];
  const float* gate_b = (const float*)d_in[24];
  const float* out_w  = (const float*)d_in[25];
  const float* out_b  = (const float*)d_in[26];
  (void)in_sizes; (void)n_in; (void)out_size; (void)ws_size;

  char* wsb = (char*)d_ws;
  size_t off = 0;
  auto alloc = [&](size_t bytes) -> void* {
    void* p = wsb + off;
    off += (bytes + 255) & ~(size_t)255;
    return p;
  };
  // persistent
  f16* hA      = (f16*)alloc((size_t)B_ * T_ * H_ * 2);   // 67 MB, in-place pipeline
  f16* wpk0    = (f16*)alloc((size_t)1024 * 512 * 2);
  f16* wpk1    = (f16*)alloc((size_t)1024 * 512 * 2);
  f16* attninf = (f16*)alloc((size_t)256 * 256 * 2);
  f16* attnoutf= (f16*)alloc((size_t)256 * 256 * 2);
  f16* gnnwf   = (f16*)alloc((size_t)256 * 256 * 2);
  f16* gatewf  = (f16*)alloc((size_t)256 * 512 * 2);
  float* bias0 = (float*)alloc(1024 * 4);
  float* bias1 = (float*)alloc(1024 * 4);
  size_t off_tail = off;            // region below reused: wb aliases post-LSTM bufs
  float* qbuf  = (float*)alloc((size_t)B_ * 256 * 4);
  float* qk    = (float*)alloc((size_t)B_ * 4 * 256 * 4);
  float* hbar  = (float*)alloc((size_t)B_ * 4 * 256 * 4);
  f16* aob     = (f16*)alloc((size_t)B_ * 256 * 2);
  float* hidden32 = (float*)alloc((size_t)B_ * 256 * 4);
  f16* hidcat  = (f16*)alloc((size_t)B_ * 512 * 2);
  f16* hT      = (f16*)alloc((size_t)256 * B_ * 2);
  f16* adjn    = (f16*)alloc((size_t)B_ * B_ * 2);
  f16* aggf    = (f16*)alloc((size_t)B_ * 256 * 2);
  float* gnnpre= (float*)alloc((size_t)B_ * 256 * 4);
  float* enr32 = (float*)alloc((size_t)B_ * 256 * 4);
  float* gatepre=(float*)alloc((size_t)B_ * 256 * 4);
  float* wb    = (float*)(wsb + off_tail);  // 9.4 MB, dead before qbuf is written

  prep_kernel<<<3336, 256, 0, stream>>>(
      Wih0, Whh0, Wih1, Whh1, bih0, bhh0, bih1, bhh1,
      attn_in_w, attn_out_w, gnn_w, gate_w,
      wpk0, wpk1, attninf, attnoutf, gnnwf, gatewf, bias0, bias1);

  // 1) VSN -> hA
  vsn_w_kernel<<<512, 256, 0, stream>>>(x, vsn_sel_w, vsn_sel_b, wb);
  vsn_h_kernel<<<1024, 256, 0, stream>>>(wb, vsn_emb_w, vsn_emb_b, hA);
  // 2) LSTM layers, fused input-proj, in place
  lstm_fused<<<64, 512, 0, stream>>>(hA, wpk0, bias0);
  lstm_fused<<<64, 512, 0, stream>>>(hA, wpk1, bias1);

  // 3) q at t=T-1
  dim3 gS(B_ / 128, 256 / 128);
  gemm_f16<<<gS, 256, 0, stream>>>(hA + (size_t)(T_ - 1) * 256, T_ * 256, attninf, 256,
                                   attn_in_b, nullptr, 0, qbuf, 256, B_, 256, 256);
  // 4) attention folded into h-space
  qk_kernel<<<B_, 256, 0, stream>>>(qbuf, attn_in_w, qk);
  attnpool_kernel<<<B_, 256, 0, stream>>>(hA, qk, hbar);
  vproj_kernel<<<B_, 256, 0, stream>>>(hbar, attn_in_w, attn_in_b, aob);
  // 5) hidden
  gemm_f16<<<gS, 256, 0, stream>>>(aob, 256, attnoutf, 256, attn_out_b,
                                   hidcat, 512, hidden32, 256, B_, 256, 256);
  // 6) GNN
  deg_adjn_kernel<<<B_, 256, 0, stream>>>(adj, sku, adjn);
  transpose_kernel<<<B_, 256, 0, stream>>>(hidden32, hT);
  gemm_f16<<<gS, 256, 0, stream>>>(adjn, 1024, hT, 1024, nullptr,
                                   aggf, 256, nullptr, 0, B_, 256, 1024);
  gemm_f16<<<gS, 256, 0, stream>>>(aggf, 256, gnnwf, 256, gnn_b,
                                   nullptr, 0, gnnpre, 256, B_, 256, 256);
  gelu_ln_kernel<<<B_, 256, 0, stream>>>(gnnpre, ln_g, ln_b, enr32, hidcat);
  // 7) gate + output
  gemm_f16<<<gS, 256, 0, stream>>>(hidcat, 512, gatewf, 512, gate_b,
                                   nullptr, 0, gatepre, 256, B_, 256, 512);
  final_kernel<<<B_, 256, 0, stream>>>(gatepre, enr32, hidden32, out_w, out_b, (float*)d_out);
}

// Round 5
// 5958.526 us; speedup vs baseline: 1.2755x; 1.2455x over previous
//
#include <hip/hip_runtime.h>
#include <hip/hip_fp16.h>

typedef _Float16 f16;
typedef _Float16 f16x8 __attribute__((ext_vector_type(8)));
typedef _Float16 f16x4 __attribute__((ext_vector_type(4)));
typedef float f32x4 __attribute__((ext_vector_type(4)));

#define B_ 1024
#define T_ 128
#define F_ 9
#define H_ 256
#define P_ 2048

// ---------------- helpers ----------------
__device__ __forceinline__ float sigf(float x) { return 1.f / (1.f + __expf(-x)); }
__device__ __forceinline__ float tanh_(float x) {
  float a = fminf(fabsf(x), 12.f);
  float e = __expf(2.f * a);
  float r = 1.f - 2.f / (e + 1.f);
  return copysignf(r, x);
}

__device__ __forceinline__ float blk_sum(float v) {
  __shared__ float sh[8];
  int lane = threadIdx.x & 63, w = threadIdx.x >> 6;
  int nw = blockDim.x >> 6;
#pragma unroll
  for (int o = 32; o > 0; o >>= 1) v += __shfl_xor(v, o, 64);
  __syncthreads();
  if (lane == 0) sh[w] = v;
  __syncthreads();
  float t = 0.f;
  for (int i = 0; i < nw; i++) t += sh[i];
  return t;
}

// ---------------- generic fp16 MFMA GEMM ----------------
__global__ __launch_bounds__(256) void gemm_f16(
    const f16* __restrict__ A, int lda,
    const f16* __restrict__ Bt, int ldb,
    const float* __restrict__ bias,
    f16* __restrict__ o16, int ldo16,
    float* __restrict__ o32, int ldo32,
    int M, int N, int K)
{
  __shared__ __align__(16) f16 As[128][40];
  __shared__ __align__(16) f16 Bs[128][40];
  const int tid = threadIdx.x;
  const int lane = tid & 63, wave = tid >> 6;
  const int wr = (wave >> 1) * 64, wc = (wave & 1) * 64;
  const int q = lane >> 4, l15 = lane & 15;
  const int bm = blockIdx.x * 128, bn = blockIdx.y * 128;

  f32x4 acc[4][4];
#pragma unroll
  for (int i = 0; i < 4; i++)
#pragma unroll
    for (int j = 0; j < 4; j++) acc[i][j] = (f32x4){0.f, 0.f, 0.f, 0.f};

  for (int k0 = 0; k0 < K; k0 += 32) {
#pragma unroll
    for (int c = 0; c < 2; ++c) {
      int ch = tid + c * 256;
      int row = ch >> 2, kh = (ch & 3) * 8;
      *(f16x8*)&As[row][kh] = *(const f16x8*)&A[(size_t)(bm + row) * lda + k0 + kh];
      *(f16x8*)&Bs[row][kh] = *(const f16x8*)&Bt[(size_t)(bn + row) * ldb + k0 + kh];
    }
    __syncthreads();
    f16x8 af[4], bf[4];
#pragma unroll
    for (int tm = 0; tm < 4; tm++) af[tm] = *(const f16x8*)&As[wr + tm * 16 + l15][q * 8];
#pragma unroll
    for (int tn = 0; tn < 4; tn++) bf[tn] = *(const f16x8*)&Bs[wc + tn * 16 + l15][q * 8];
#pragma unroll
    for (int tm = 0; tm < 4; tm++)
#pragma unroll
      for (int tn = 0; tn < 4; tn++)
        acc[tm][tn] = __builtin_amdgcn_mfma_f32_16x16x32_f16(af[tm], bf[tn], acc[tm][tn], 0, 0, 0);
    __syncthreads();
  }
#pragma unroll
  for (int tm = 0; tm < 4; tm++) {
#pragma unroll
    for (int tn = 0; tn < 4; tn++) {
      int colg = bn + wc + tn * 16 + l15;
      float bv = bias ? bias[colg] : 0.f;
#pragma unroll
      for (int r = 0; r < 4; r++) {
        int rowg = bm + wr + tm * 16 + q * 4 + r;
        float v = acc[tm][tn][r] + bv;
        if (o32) o32[(size_t)rowg * ldo32 + colg] = v;
        if (o16) o16[(size_t)rowg * ldo16 + colg] = (f16)v;
      }
    }
  }
}

// ---------------- LSTM: register-resident weights + 4-block groups ----------------
// grid 256 = 64 row-groups (16 rows) x 4 col-slices (64 cols). 256 threads.
// Weights (this block's slice: 4 gates x 64 cols x 512 K = 256 KB) live in
// VGPRs for the whole 128-step scan -> zero weight traffic per step.
// h exchange among the 4 group blocks goes through hio + a 2-phase
// device-scope counter protocol (release add / acquire spin).
// grp = bid & 63 -> group members differ by 64 (same XCD under %8 round-robin,
// L2-local exchange; correctness independent of mapping).
__global__ __launch_bounds__(256, 1) void lstm_sync(
    f16* __restrict__ hio,
    const f16* __restrict__ wpk,     // packed [s(4)][w(4)][g(4)][k(16)][lane(64)][8]
    const float* __restrict__ bias,
    int* __restrict__ cnt)           // [64], zeroed before launch
{
  __shared__ __align__(16) f16 apf[16][64][8];   // A-frags [k][lane][8], 16 KB
  __shared__ __align__(16) f16 htile[16][64];    // h staging for coalesced store
  const int tid = threadIdx.x;
  const int lane = tid & 63, w = tid >> 6;       // wave 0..3
  const int q = lane >> 4, l15 = lane & 15;
  const int grp = blockIdx.x & 63, s = blockIdx.x >> 6;
  const int m0 = grp * 16;
  int* mycnt = cnt + grp;

  // ---- load weight slice into registers: 64 x f16x8 = 256 VGPRs ----
  f16x8 bf[4][16];
  {
    const f16* wbase = wpk + (((size_t)(s * 4 + w) * 4) * 16) * 512 + lane * 8;
#pragma unroll
    for (int g = 0; g < 4; g++)
#pragma unroll
      for (int k = 0; k < 16; k++)
        bf[g][k] = *(const f16x8*)(wbase + (size_t)(g * 16 + k) * 512);
  }
  float bv[4];
#pragma unroll
  for (int g = 0; g < 4; g++) bv[g] = bias[g * 256 + s * 64 + w * 16 + l15];

  // staging map: chunk c in [0,512): row=c>>5, cc=c&31 (8 cols each).
  // this thread handles chunks tid (r0) and tid+256 (r1=r0+8), same cc.
  const int r0 = tid >> 5, cc = tid & 31;
  const int r1 = r0 + 8;
  const int dk = cc >> 2, dl = (cc & 3) * 16;    // apf[dk][dl+row]
  const size_t row0base = ((size_t)(m0 + r0) * T_) * 256 + cc * 8;
  const size_t row1base = ((size_t)(m0 + r1) * T_) * 256 + cc * 8;

  const f16x8 zv = {(f16)0, (f16)0, (f16)0, (f16)0, (f16)0, (f16)0, (f16)0, (f16)0};
  f16x8 xr0 = *(const f16x8*)&hio[row0base];     // x at t=0
  f16x8 xr1 = *(const f16x8*)&hio[row1base];
  float cst[4] = {0.f, 0.f, 0.f, 0.f};

  for (int t = 0; t < T_; ++t) {
    // ---- phase A: wait for h_{t-1} writes of all 4 group blocks ----
    if (t > 0) {
      if (tid == 0) {
        int it = 0;
        while (__hip_atomic_load(mycnt, __ATOMIC_ACQUIRE, __HIP_MEMORY_SCOPE_AGENT) < 8 * t) {
          __builtin_amdgcn_s_sleep(1);
          if (++it > (1 << 27)) break;   // bailout: wrong answer beats a hang
        }
      }
      __syncthreads();
    }
    // stage h_{t-1} (global, written by group last step) and x_t (prefetched)
    f16x8 h0 = zv, h1 = zv;
    if (t > 0) {
      h0 = *(const f16x8*)&hio[row0base + (size_t)(t - 1) * 256];
      h1 = *(const f16x8*)&hio[row1base + (size_t)(t - 1) * 256];
    }
    *(f16x8*)&apf[dk][dl + r0][0] = xr0;
    *(f16x8*)&apf[dk][dl + r1][0] = xr1;
    *(f16x8*)&apf[8 + dk][dl + r0][0] = h0;
    *(f16x8*)&apf[8 + dk][dl + r1][0] = h1;
    __syncthreads();
    if (tid == 0)  // signal "staged x_t" -> peers may overwrite slot t with h_t
      __hip_atomic_fetch_add(mycnt, 1, __ATOMIC_RELEASE, __HIP_MEMORY_SCOPE_AGENT);

    // ---- compute: 64 MFMAs, B-operands from registers ----
    f32x4 acc[4];
#pragma unroll
    for (int g = 0; g < 4; g++) acc[g] = (f32x4){0.f, 0.f, 0.f, 0.f};
#pragma unroll
    for (int k = 0; k < 16; k++) {
      f16x8 a = *(const f16x8*)&apf[k][lane][0];
#pragma unroll
      for (int g = 0; g < 4; g++)
        acc[g] = __builtin_amdgcn_mfma_f32_16x16x32_f16(a, bf[g][k], acc[g], 0, 0, 0);
    }
    // prefetch x_{t+1} (slot t+1 is stable until all blocks stage step t+1)
    if (t + 1 < T_) {
      xr0 = *(const f16x8*)&hio[row0base + (size_t)(t + 1) * 256];
      xr1 = *(const f16x8*)&hio[row1base + (size_t)(t + 1) * 256];
    }
    // gate math (lane holds rows q*4+r, col s*64+w*16+l15 of every gate)
    f16 hn[4];
#pragma unroll
    for (int r = 0; r < 4; r++) {
      float ip = acc[0][r] + bv[0];
      float fp = acc[1][r] + bv[1];
      float gp = acc[2][r] + bv[2];
      float op = acc[3][r] + bv[3];
      float cn = sigf(fp) * cst[r] + sigf(ip) * tanh_(gp);
      cst[r] = cn;
      hn[r] = (f16)(sigf(op) * tanh_(cn));
    }
    __syncthreads();                 // htile reuse + apf reads done
#pragma unroll
    for (int r = 0; r < 4; r++) htile[q * 4 + r][w * 16 + l15] = hn[r];
    // ---- phase B: wait until all 4 blocks staged x_t, then write h_t ----
    if (tid == 0) {
      int it = 0;
      while (__hip_atomic_load(mycnt, __ATOMIC_ACQUIRE, __HIP_MEMORY_SCOPE_AGENT) < 8 * t + 4) {
        __builtin_amdgcn_s_sleep(1);
        if (++it > (1 << 27)) break;
      }
    }
    __syncthreads();                 // htile ready + spin done
    {
      int row = tid >> 4, c4 = (tid & 15) * 4;
      *(f16x4*)&hio[((size_t)(m0 + row) * T_ + t) * 256 + s * 64 + c4] =
          *(const f16x4*)&htile[row][c4];
    }
    __syncthreads();                 // all h stores issued (vmcnt drained)
    if (tid == 0) {
      __threadfence();               // agent release: L2 writeback
      __hip_atomic_fetch_add(mycnt, 1, __ATOMIC_RELEASE, __HIP_MEMORY_SCOPE_AGENT);
    }
  }
}

// ---------------- VSN, two-phase ----------------
__global__ __launch_bounds__(256) void vsn_w_kernel(
    const float* __restrict__ x, const float* __restrict__ selw,
    const float* __restrict__ selb, float* __restrict__ wb)
{
  int pos = blockIdx.x * 256 + threadIdx.x;
  const float* xr = x + (size_t)pos * F_;
  float xv[F_];
#pragma unroll
  for (int f = 0; f < F_; f++) xv[f] = xr[f];
  float wv[F_]; float mx = -1e30f;
#pragma unroll
  for (int f = 0; f < F_; f++) {
    float s = selb[f];
#pragma unroll
    for (int f2 = 0; f2 < F_; f2++) s += xv[f2] * selw[f * F_ + f2];
    wv[f] = s; mx = fmaxf(mx, s);
  }
  float se = 0.f;
#pragma unroll
  for (int f = 0; f < F_; f++) { wv[f] = __expf(wv[f] - mx); se += wv[f]; }
  float inv = 1.f / se;
  float* o = wb + (size_t)pos * 18;
#pragma unroll
  for (int f = 0; f < F_; f++) {
    float wt = wv[f] * inv;
    o[f] = wt; o[9 + f] = wt * xv[f];
  }
}

__global__ __launch_bounds__(256) void vsn_h_kernel(
    const float* __restrict__ wb, const float* __restrict__ embw,
    const float* __restrict__ embb, f16* __restrict__ hout)
{
  int j = threadIdx.x;
  float ew[F_], eb[F_];
#pragma unroll
  for (int f = 0; f < F_; f++) { ew[f] = embw[f * H_ + j]; eb[f] = embb[f * H_ + j]; }
  for (int i = 0; i < 128; i++) {
    size_t pos = blockIdx.x + (size_t)i * 1024;
    const float* w = wb + pos * 18;
    float h = 0.f;
#pragma unroll
    for (int f = 0; f < F_; f++) h += w[9 + f] * ew[f] + w[f] * eb[f];
    hout[pos * H_ + j] = (f16)h;
  }
}

// ---------------- attention in h-space ----------------
__global__ __launch_bounds__(256) void qk_kernel(
    const float* __restrict__ qbuf, const float* __restrict__ attn_in_w,
    float* __restrict__ qk)
{
  __shared__ float qs[256];
  int b = blockIdx.x, j = threadIdx.x;
  qs[j] = qbuf[(size_t)b * 256 + j];
  __syncthreads();
#pragma unroll
  for (int h = 0; h < 4; h++) {
    float acc = 0.f;
    for (int d = 0; d < 64; d++)
      acc += qs[h * 64 + d] * attn_in_w[(size_t)(256 + h * 64 + d) * 256 + j];
    qk[((size_t)b * 4 + h) * 256 + j] = acc * 0.125f;
  }
}

__global__ __launch_bounds__(256) void attnpool_kernel(
    const f16* __restrict__ hseq, const float* __restrict__ qk,
    float* __restrict__ hbar)
{
  __shared__ __align__(16) f16 hs[T_][264];
  __shared__ float qks[4][256];
  __shared__ float ps[4][T_];
  int b = blockIdx.x, tid = threadIdx.x;
  for (int i = tid; i < T_ * 32; i += 256) {
    int row = i >> 5, cc = (i & 31) * 8;
    *(f16x8*)&hs[row][cc] = *(const f16x8*)&hseq[((size_t)b * T_ + row) * 256 + cc];
  }
  for (int i = tid; i < 1024; i += 256) qks[i >> 8][i & 255] = qk[(size_t)b * 1024 + i];
  __syncthreads();
  if (tid < T_) {
    float s[4] = {0.f, 0.f, 0.f, 0.f};
    for (int cc = 0; cc < 32; cc++) {
      f16x8 v = *(const f16x8*)&hs[tid][cc * 8];
#pragma unroll
      for (int h = 0; h < 4; h++) {
        float a = 0.f;
#pragma unroll
        for (int j = 0; j < 8; j++) a += qks[h][cc * 8 + j] * (float)v[j];
        s[h] += a;
      }
    }
#pragma unroll
    for (int h = 0; h < 4; h++) ps[h][tid] = s[h];
  }
  __syncthreads();
  {
    int w = tid >> 6, l = tid & 63;
    float a = ps[w][l], bb = ps[w][l + 64];
    float m = fmaxf(a, bb);
#pragma unroll
    for (int o = 32; o > 0; o >>= 1) m = fmaxf(m, __shfl_xor(m, o, 64));
    float e0 = __expf(a - m), e1 = __expf(bb - m);
    float se = e0 + e1;
#pragma unroll
    for (int o = 32; o > 0; o >>= 1) se += __shfl_xor(se, o, 64);
    float inv = 1.f / se;
    ps[w][l] = e0 * inv; ps[w][l + 64] = e1 * inv;
  }
  __syncthreads();
  int j = tid;
  float acc[4] = {0.f, 0.f, 0.f, 0.f};
  for (int t = 0; t < T_; t++) {
    float hv = (float)hs[t][j];
#pragma unroll
    for (int h = 0; h < 4; h++) acc[h] += ps[h][t] * hv;
  }
#pragma unroll
  for (int h = 0; h < 4; h++) hbar[((size_t)b * 4 + h) * 256 + j] = acc[h];
}

__global__ __launch_bounds__(256) void vproj_kernel(
    const float* __restrict__ hbar, const float* __restrict__ attn_in_w,
    const float* __restrict__ attn_in_b, f16* __restrict__ aob)
{
  __shared__ float hb[4][256];
  int b = blockIdx.x, tid = threadIdx.x;
  for (int i = tid; i < 1024; i += 256) hb[i >> 8][i & 255] = hbar[(size_t)b * 1024 + i];
  __syncthreads();
  int d = tid, h = d >> 6;
  const float4* wr = (const float4*)(attn_in_w + (size_t)(512 + d) * 256);
  float acc = 0.f;
  for (int cc = 0; cc < 64; cc++) {
    float4 w4 = wr[cc];
    acc += w4.x * hb[h][cc * 4] + w4.y * hb[h][cc * 4 + 1]
         + w4.z * hb[h][cc * 4 + 2] + w4.w * hb[h][cc * 4 + 3];
  }
  aob[(size_t)b * 256 + d] = (f16)(acc + attn_in_b[512 + d]);
}

// ---------------- GNN prep ----------------
__global__ __launch_bounds__(256) void deg_adjn_kernel(
    const float* __restrict__ adj, const int* __restrict__ sku,
    f16* __restrict__ adjn)
{
  int bp = blockIdx.x;
  int p = sku[bp];
  int tid = threadIdx.x;
  float s = 0.f;
  for (int j = tid; j < P_; j += 256) s += adj[(size_t)p * P_ + j];
  float tot = blk_sum(s);
  float inv = 1.f / fmaxf(tot, 1e-6f);
  for (int b = tid; b < B_; b += 256)
    adjn[(size_t)bp * B_ + b] = (f16)(adj[(size_t)p * P_ + sku[b]] * inv);
}

__global__ void transpose_kernel(const float* __restrict__ hid, f16* __restrict__ hT)
{
  int i = blockIdx.x * 256 + threadIdx.x;
  int b = i >> 8, j = i & 255;
  hT[(size_t)j * B_ + b] = (f16)hid[i];
}

__global__ __launch_bounds__(256) void gelu_ln_kernel(
    const float* __restrict__ pre, const float* __restrict__ lg,
    const float* __restrict__ lb, float* __restrict__ enr,
    f16* __restrict__ hidcat)
{
  int row = blockIdx.x, j = threadIdx.x;
  float xv = pre[row * 256 + j];
  float ge = 0.5f * xv * (1.f + erff(xv * 0.70710678118654752f));
  float mu = blk_sum(ge) * (1.f / 256.f);
  float d = ge - mu;
  float var = blk_sum(d * d) * (1.f / 256.f);
  float y = d * rsqrtf(var + 1e-5f) * lg[j] + lb[j];
  enr[row * 256 + j] = y;
  hidcat[row * 512 + 256 + j] = (f16)y;
}

__global__ __launch_bounds__(256) void final_kernel(
    const float* __restrict__ gpre, const float* __restrict__ enr,
    const float* __restrict__ hid, const float* __restrict__ outw,
    const float* __restrict__ outb, float* __restrict__ out)
{
  int b = blockIdx.x, j = threadIdx.x;
  float gt = sigf(gpre[b * 256 + j]);
  float comb = gt * enr[b * 256 + j] + (1.f - gt) * hid[b * 256 + j];
  float v = comb * outw[j];
  float s = blk_sum(v);
  if (j == 0) out[b] = s + outb[0];
}

// ---------------- one-shot weight prep ----------------
// wpk layout: elem = ((((s*4+w)*4+g)*16+k)*64+lane)*8 + j
// row = g*256 + s*64 + w*16 + (lane&15); col = k*32 + (lane>>4)*8 + j
// threads: 524288 + 3*65536 + 131072 + 2*1024 = 854016 = 3336 blocks
__global__ void prep_kernel(
    const float* Wih0, const float* Whh0, const float* Wih1, const float* Whh1,
    const float* bih0, const float* bhh0, const float* bih1, const float* bhh1,
    const float* attn_in_w, const float* attn_out_w, const float* gnn_w,
    const float* gate_w,
    f16* wpk0, f16* wpk1, f16* attninf, f16* attnoutf, f16* gnnwf, f16* gatewf,
    float* bias0, float* bias1)
{
  int idx = blockIdx.x * 256 + threadIdx.x;
  if (idx < 524288) {
    int j = idx & 7, lane = (idx >> 3) & 63, k = (idx >> 9) & 15;
    int g = (idx >> 13) & 3, w = (idx >> 15) & 3, s = (idx >> 17) & 3;
    int row = g * 256 + s * 64 + w * 16 + (lane & 15);
    int col = k * 32 + (lane >> 4) * 8 + j;
    float v0 = col < 256 ? Wih0[(size_t)row * 256 + col] : Whh0[(size_t)row * 256 + col - 256];
    float v1 = col < 256 ? Wih1[(size_t)row * 256 + col] : Whh1[(size_t)row * 256 + col - 256];
    wpk0[idx] = (f16)v0;
    wpk1[idx] = (f16)v1;
    return;
  }
  int i = idx - 524288;
  if (i < 65536) { attninf[i] = (f16)attn_in_w[i]; return; }
  i -= 65536;
  if (i < 65536) { attnoutf[i] = (f16)attn_out_w[i]; return; }
  i -= 65536;
  if (i < 65536) { gnnwf[i] = (f16)gnn_w[i]; return; }
  i -= 65536;
  if (i < 131072) { gatewf[i] = (f16)gate_w[i]; return; }
  i -= 131072;
  if (i < 1024) { bias0[i] = bih0[i] + bhh0[i]; return; }
  i -= 1024;
  if (i < 1024) { bias1[i] = bih1[i] + bhh1[i]; return; }
}

// ---------------- launch ----------------
extern "C" void kernel_launch(void* const* d_in, const int* in_sizes, int n_in,
                              void* d_out, int out_size, void* d_ws, size_t ws_size,
                              hipStream_t stream)
{
  const float* x         = (const float*)d_in[0];
  const int*   sku       = (const int*)  d_in[1];
  const float* adj       = (const float*)d_in[2];
  const float* vsn_emb_w = (const float*)d_in[3];
  const float* vsn_emb_b = (const float*)d_in[4];
  const float* vsn_sel_w = (const float*)d_in[5];
  const float* vsn_sel_b = (const float*)d_in[6];
  const float* Wih0 = (const float*)d_in[7];
  const float* Whh0 = (const float*)d_in[8];
  const float* bih0 = (const float*)d_in[9];
  const float* bhh0 = (const float*)d_in[10];
  const float* Wih1 = (const float*)d_in[11];
  const float* Whh1 = (const float*)d_in[12];
  const float* bih1 = (const float*)d_in[13];
  const float* bhh1 = (const float*)d_in[14];
  const float* attn_in_w  = (const float*)d_in[15];
  const float* attn_in_b  = (const float*)d_in[16];
  const float* attn_out_w = (const float*)d_in[17];
  const float* attn_out_b = (const float*)d_in[18];
  const float* gnn_w  = (const float*)d_in[19];
  const float* gnn_b  = (const float*)d_in[20];
  const float* ln_g   = (const float*)d_in[21];
  const float* ln_b   = (const float*)d_in[22];
  const float* gate_w = (const float*)d_in[23];
  const float* gate_b = (const float*)d_in[24];
  const float* out_w  = (const float*)d_in[25];
  const float* out_b  = (const float*)d_in[26];
  (void)in_sizes; (void)n_in; (void)out_size; (void)ws_size;

  char* wsb = (char*)d_ws;
  size_t off = 0;
  auto alloc = [&](size_t bytes) -> void* {
    void* p = wsb + off;
    off += (bytes + 255) & ~(size_t)255;
    return p;
  };
  // persistent
  f16* hA      = (f16*)alloc((size_t)B_ * T_ * H_ * 2);   // 67 MB, in-place pipeline
  f16* wpk0    = (f16*)alloc((size_t)1024 * 512 * 2);
  f16* wpk1    = (f16*)alloc((size_t)1024 * 512 * 2);
  f16* attninf = (f16*)alloc((size_t)256 * 256 * 2);
  f16* attnoutf= (f16*)alloc((size_t)256 * 256 * 2);
  f16* gnnwf   = (f16*)alloc((size_t)256 * 256 * 2);
  f16* gatewf  = (f16*)alloc((size_t)256 * 512 * 2);
  float* bias0 = (float*)alloc(1024 * 4);
  float* bias1 = (float*)alloc(1024 * 4);
  int* cnt0    = (int*)alloc(64 * 4);
  int* cnt1    = (int*)alloc(64 * 4);
  size_t off_tail = off;            // region below reused: wb aliases post-LSTM bufs
  float* qbuf  = (float*)alloc((size_t)B_ * 256 * 4);
  float* qk    = (float*)alloc((size_t)B_ * 4 * 256 * 4);
  float* hbar  = (float*)alloc((size_t)B_ * 4 * 256 * 4);
  f16* aob     = (f16*)alloc((size_t)B_ * 256 * 2);
  float* hidden32 = (float*)alloc((size_t)B_ * 256 * 4);
  f16* hidcat  = (f16*)alloc((size_t)B_ * 512 * 2);
  f16* hT      = (f16*)alloc((size_t)256 * B_ * 2);
  f16* adjn    = (f16*)alloc((size_t)B_ * B_ * 2);
  f16* aggf    = (f16*)alloc((size_t)B_ * 256 * 2);
  float* gnnpre= (float*)alloc((size_t)B_ * 256 * 4);
  float* enr32 = (float*)alloc((size_t)B_ * 256 * 4);
  float* gatepre=(float*)alloc((size_t)B_ * 256 * 4);
  float* wb    = (float*)(wsb + off_tail);  // 9.4 MB, dead before qbuf is written

  // zero the group counters (ws is re-poisoned 0xAA before every launch)
  hipMemsetAsync(cnt0, 0, 2 * 64 * 4, stream);

  prep_kernel<<<3336, 256, 0, stream>>>(
      Wih0, Whh0, Wih1, Whh1, bih0, bhh0, bih1, bhh1,
      attn_in_w, attn_out_w, gnn_w, gate_w,
      wpk0, wpk1, attninf, attnoutf, gnnwf, gatewf, bias0, bias1);

  // 1) VSN -> hA
  vsn_w_kernel<<<512, 256, 0, stream>>>(x, vsn_sel_w, vsn_sel_b, wb);
  vsn_h_kernel<<<1024, 256, 0, stream>>>(wb, vsn_emb_w, vsn_emb_b, hA);
  // 2) LSTM layers, register-resident weights, in place
  lstm_sync<<<256, 256, 0, stream>>>(hA, wpk0, bias0, cnt0);
  lstm_sync<<<256, 256, 0, stream>>>(hA, wpk1, bias1, cnt1);

  // 3) q at t=T-1
  dim3 gS(B_ / 128, 256 / 128);
  gemm_f16<<<gS, 256, 0, stream>>>(hA + (size_t)(T_ - 1) * 256, T_ * 256, attninf, 256,
                                   attn_in_b, nullptr, 0, qbuf, 256, B_, 256, 256);
  // 4) attention folded into h-space
  qk_kernel<<<B_, 256, 0, stream>>>(qbuf, attn_in_w, qk);
  attnpool_kernel<<<B_, 256, 0, stream>>>(hA, qk, hbar);
  vproj_kernel<<<B_, 256, 0, stream>>>(hbar, attn_in_w, attn_in_b, aob);
  // 5) hidden
  gemm_f16<<<gS, 256, 0, stream>>>(aob, 256, attnoutf, 256, attn_out_b,
                                   hidcat, 512, hidden32, 256, B_, 256, 256);
  // 6) GNN
  deg_adjn_kernel<<<B_, 256, 0, stream>>>(adj, sku, adjn);
  transpose_kernel<<<B_, 256, 0, stream>>>(hidden32, hT);
  gemm_f16<<<gS, 256, 0, stream>>>(adjn, 1024, hT, 1024, nullptr,
                                   aggf, 256, nullptr, 0, B_, 256, 1024);
  gemm_f16<<<gS, 256, 0, stream>>>(aggf, 256, gnnwf, 256, gnn_b,
                                   nullptr, 0, gnnpre, 256, B_, 256, 256);
  gelu_ln_kernel<<<B_, 256, 0, stream>>>(gnnpre, ln_g, ln_b, enr32, hidcat);
  // 7) gate + output
  gemm_f16<<<gS, 256, 0, stream>>>(hidcat, 512, gatewf, 512, gate_b,
                                   nullptr, 0, gatepre, 256, B_, 256, 512);
  final_kernel<<<B_, 256, 0, stream>>>(gatepre, enr32, hidden32, out_w, out_b, (float*)d_out);
}

// Round 6
// 3336.157 us; speedup vs baseline: 2.2781x; 1.7860x over previous
//
#include <hip/hip_runtime.h>
#include <hip/hip_fp16.h>

typedef _Float16 f16;
typedef _Float16 f16x8 __attribute__((ext_vector_type(8)));
typedef _Float16 f16x4 __attribute__((ext_vector_type(4)));
typedef float f32x4 __attribute__((ext_vector_type(4)));

#define B_ 1024
#define T_ 128
#define F_ 9
#define H_ 256
#define P_ 2048

// ---------------- helpers ----------------
__device__ __forceinline__ float sigf(float x) { return 1.f / (1.f + __expf(-x)); }
__device__ __forceinline__ float tanh_(float x) {
  float a = fminf(fabsf(x), 12.f);
  float e = __expf(2.f * a);
  float r = 1.f - 2.f / (e + 1.f);
  return copysignf(r, x);
}

__device__ __forceinline__ float blk_sum(float v) {
  __shared__ float sh[8];
  int lane = threadIdx.x & 63, w = threadIdx.x >> 6;
  int nw = blockDim.x >> 6;
#pragma unroll
  for (int o = 32; o > 0; o >>= 1) v += __shfl_xor(v, o, 64);
  __syncthreads();
  if (lane == 0) sh[w] = v;
  __syncthreads();
  float t = 0.f;
  for (int i = 0; i < nw; i++) t += sh[i];
  return t;
}

// ---------------- generic fp16 MFMA GEMM ----------------
__global__ __launch_bounds__(256) void gemm_f16(
    const f16* __restrict__ A, int lda,
    const f16* __restrict__ Bt, int ldb,
    const float* __restrict__ bias,
    f16* __restrict__ o16, int ldo16,
    float* __restrict__ o32, int ldo32,
    int M, int N, int K)
{
  __shared__ __align__(16) f16 As[128][40];
  __shared__ __align__(16) f16 Bs[128][40];
  const int tid = threadIdx.x;
  const int lane = tid & 63, wave = tid >> 6;
  const int wr = (wave >> 1) * 64, wc = (wave & 1) * 64;
  const int q = lane >> 4, l15 = lane & 15;
  const int bm = blockIdx.x * 128, bn = blockIdx.y * 128;

  f32x4 acc[4][4];
#pragma unroll
  for (int i = 0; i < 4; i++)
#pragma unroll
    for (int j = 0; j < 4; j++) acc[i][j] = (f32x4){0.f, 0.f, 0.f, 0.f};

  for (int k0 = 0; k0 < K; k0 += 32) {
#pragma unroll
    for (int c = 0; c < 2; ++c) {
      int ch = tid + c * 256;
      int row = ch >> 2, kh = (ch & 3) * 8;
      *(f16x8*)&As[row][kh] = *(const f16x8*)&A[(size_t)(bm + row) * lda + k0 + kh];
      *(f16x8*)&Bs[row][kh] = *(const f16x8*)&Bt[(size_t)(bn + row) * ldb + k0 + kh];
    }
    __syncthreads();
    f16x8 af[4], bf[4];
#pragma unroll
    for (int tm = 0; tm < 4; tm++) af[tm] = *(const f16x8*)&As[wr + tm * 16 + l15][q * 8];
#pragma unroll
    for (int tn = 0; tn < 4; tn++) bf[tn] = *(const f16x8*)&Bs[wc + tn * 16 + l15][q * 8];
#pragma unroll
    for (int tm = 0; tm < 4; tm++)
#pragma unroll
      for (int tn = 0; tn < 4; tn++)
        acc[tm][tn] = __builtin_amdgcn_mfma_f32_16x16x32_f16(af[tm], bf[tn], acc[tm][tn], 0, 0, 0);
    __syncthreads();
  }
#pragma unroll
  for (int tm = 0; tm < 4; tm++) {
#pragma unroll
    for (int tn = 0; tn < 4; tn++) {
      int colg = bn + wc + tn * 16 + l15;
      float bv = bias ? bias[colg] : 0.f;
#pragma unroll
      for (int r = 0; r < 4; r++) {
        int rowg = bm + wr + tm * 16 + q * 4 + r;
        float v = acc[tm][tn][r] + bv;
        if (o32) o32[(size_t)rowg * ldo32 + colg] = v;
        if (o16) o16[(size_t)rowg * ldo16 + colg] = (f16)v;
      }
    }
  }
}

// ---------------- LSTM: register weights, 1 handshake/step, padded counters --------
// grid 256 = 64 row-groups (16 rows) x 4 col-slices (64 cols), 256 threads.
// Weight slice (256 KB) in VGPRs/AGPRs for the whole scan. In-place on hio.
// Protocol invariant: block signals step t only after (a) its h_t stores are
// drained (syncthreads drains vmcnt before s_barrier) and (b) its x_{t+1}
// prefetch loads completed. Hence phase-A (cnt >= 4(t+1)) implies every peer
// holds x_t in registers -> clobbering slot t with h_t is safe. One signal
// per step; counters padded to 256B to kill cross-group line ping-pong.
__global__ __launch_bounds__(256, 1) void lstm_sync(
    f16* __restrict__ hio,
    const f16* __restrict__ wpk,     // packed [s(4)][w(4)][g(4)][k(16)][lane(64)][8]
    const float* __restrict__ bias,
    int* __restrict__ cnt)           // one int per group, stride 64 ints (256B)
{
  __shared__ __align__(16) f16 apf[16][64][8];   // A-frags [k][lane][8], 16 KB
  __shared__ __align__(16) f16 htile[16][64];
  const int tid = threadIdx.x;
  const int lane = tid & 63, w = tid >> 6;       // wave 0..3
  const int q = lane >> 4, l15 = lane & 15;
  const int grp = blockIdx.x & 63, s = blockIdx.x >> 6;
  const int m0 = grp * 16;
  int* mycnt = cnt + grp * 64;

  // ---- weight slice into registers: 64 x f16x8 = 256 regs/lane ----
  f16x8 bf[4][16];
  {
    const f16* wbase = wpk + (((size_t)(s * 4 + w) * 4) * 16) * 512 + lane * 8;
#pragma unroll
    for (int g = 0; g < 4; g++)
#pragma unroll
      for (int k = 0; k < 16; k++)
        bf[g][k] = *(const f16x8*)(wbase + (size_t)(g * 16 + k) * 512);
  }
  float bv[4];
#pragma unroll
  for (int g = 0; g < 4; g++) bv[g] = bias[g * 256 + s * 64 + w * 16 + l15];

  // staging geometry: thread owns exactly its own A-frag slots apf[k][lane]
  // for k in {w, w+4} (x halves) and {8+w, 12+w} (h halves).
  // element (row=lane&15, col=k*32+(lane>>4)*8+j) -> conflict-free b128 LDS.
  const int srow = lane & 15, scb = lane >> 4;
  const size_t rowbase = ((size_t)(m0 + srow) * T_) * 256 + scb * 8;

  const f16x8 zv = {(f16)0, (f16)0, (f16)0, (f16)0, (f16)0, (f16)0, (f16)0, (f16)0};
  f16x8 xr0 = *(const f16x8*)&hio[rowbase + (size_t)w * 32];         // x_0
  f16x8 xr1 = *(const f16x8*)&hio[rowbase + (size_t)(w + 4) * 32];
  float cst[4] = {0.f, 0.f, 0.f, 0.f};

  __syncthreads();                   // drains all lanes' x_0 loads (vmcnt 0)
  if (tid == 0)                      // initial signal: x_0 prefetched
    __hip_atomic_fetch_add(mycnt, 1, __ATOMIC_RELEASE, __HIP_MEMORY_SCOPE_AGENT);

  for (int t = 0; t < T_; ++t) {
    // phase A: everyone finished step t-1 (initial signal counts as step -1)
    if (tid == 0) {
      int it = 0;
      while (__hip_atomic_load(mycnt, __ATOMIC_ACQUIRE, __HIP_MEMORY_SCOPE_AGENT) < 4 * t + 4) {
        __builtin_amdgcn_s_sleep(1);
        if (++it > (1 << 26)) break;   // bailout: wrong answer beats a hang
      }
    }
    __syncthreads();
    // stage x_t (from prefetch regs) and h_{t-1} (from global, peers' writes)
    *(f16x8*)&apf[w][lane][0]     = xr0;
    *(f16x8*)&apf[w + 4][lane][0] = xr1;
    f16x8 h0 = zv, h1 = zv;
    if (t > 0) {
      h0 = *(const f16x8*)&hio[rowbase + (size_t)(t - 1) * 256 + (size_t)w * 32];
      h1 = *(const f16x8*)&hio[rowbase + (size_t)(t - 1) * 256 + (size_t)(w + 4) * 32];
    }
    *(f16x8*)&apf[8 + w][lane][0]  = h0;
    *(f16x8*)&apf[12 + w][lane][0] = h1;
    __syncthreads();

    // ---- compute: 64 MFMAs, B-operands resident in registers ----
    f32x4 acc[4];
#pragma unroll
    for (int g = 0; g < 4; g++) acc[g] = (f32x4){0.f, 0.f, 0.f, 0.f};
#pragma unroll
    for (int k = 0; k < 16; k++) {
      f16x8 a = *(const f16x8*)&apf[k][lane][0];
#pragma unroll
      for (int g = 0; g < 4; g++)
        acc[g] = __builtin_amdgcn_mfma_f32_16x16x32_f16(a, bf[g][k], acc[g], 0, 0, 0);
    }
    // prefetch x_{t+1} (slot stable: peers clobber t+1 only after our signal t)
    if (t + 1 < T_) {
      xr0 = *(const f16x8*)&hio[rowbase + (size_t)(t + 1) * 256 + (size_t)w * 32];
      xr1 = *(const f16x8*)&hio[rowbase + (size_t)(t + 1) * 256 + (size_t)(w + 4) * 32];
    }
    // gate math (lane: rows q*4+r, col s*64+w*16+l15 of each gate)
    f16 hn[4];
#pragma unroll
    for (int r = 0; r < 4; r++) {
      float ip = acc[0][r] + bv[0];
      float fp = acc[1][r] + bv[1];
      float gp = acc[2][r] + bv[2];
      float op = acc[3][r] + bv[3];
      float cn = sigf(fp) * cst[r] + sigf(ip) * tanh_(gp);
      cst[r] = cn;
      hn[r] = (f16)(sigf(op) * tanh_(cn));
    }
    __syncthreads();                 // apf reads done; htile reusable
#pragma unroll
    for (int r = 0; r < 4; r++) htile[q * 4 + r][w * 16 + l15] = hn[r];
    __syncthreads();                 // htile ready; drains xr prefetch loads
    {                                // write h_t over slot t (coalesced 128B/row)
      int row = tid >> 4, c4 = (tid & 15) * 4;
      *(f16x4*)&hio[((size_t)(m0 + row) * T_ + t) * 256 + s * 64 + c4] =
          *(const f16x4*)&htile[row][c4];
    }
    __syncthreads();                 // drains h stores from all lanes
    if (tid == 0) {
      __threadfence();               // agent release
      __hip_atomic_fetch_add(mycnt, 1, __ATOMIC_RELEASE, __HIP_MEMORY_SCOPE_AGENT);
    }
  }
}

// ---------------- VSN, two-phase ----------------
__global__ __launch_bounds__(256) void vsn_w_kernel(
    const float* __restrict__ x, const float* __restrict__ selw,
    const float* __restrict__ selb, float* __restrict__ wb)
{
  int pos = blockIdx.x * 256 + threadIdx.x;
  const float* xr = x + (size_t)pos * F_;
  float xv[F_];
#pragma unroll
  for (int f = 0; f < F_; f++) xv[f] = xr[f];
  float wv[F_]; float mx = -1e30f;
#pragma unroll
  for (int f = 0; f < F_; f++) {
    float s = selb[f];
#pragma unroll
    for (int f2 = 0; f2 < F_; f2++) s += xv[f2] * selw[f * F_ + f2];
    wv[f] = s; mx = fmaxf(mx, s);
  }
  float se = 0.f;
#pragma unroll
  for (int f = 0; f < F_; f++) { wv[f] = __expf(wv[f] - mx); se += wv[f]; }
  float inv = 1.f / se;
  float* o = wb + (size_t)pos * 18;
#pragma unroll
  for (int f = 0; f < F_; f++) {
    float wt = wv[f] * inv;
    o[f] = wt; o[9 + f] = wt * xv[f];
  }
}

__global__ __launch_bounds__(256) void vsn_h_kernel(
    const float* __restrict__ wb, const float* __restrict__ embw,
    const float* __restrict__ embb, f16* __restrict__ hout)
{
  int j = threadIdx.x;
  float ew[F_], eb[F_];
#pragma unroll
  for (int f = 0; f < F_; f++) { ew[f] = embw[f * H_ + j]; eb[f] = embb[f * H_ + j]; }
  for (int i = 0; i < 128; i++) {
    size_t pos = blockIdx.x + (size_t)i * 1024;
    const float* w = wb + pos * 18;
    float h = 0.f;
#pragma unroll
    for (int f = 0; f < F_; f++) h += w[9 + f] * ew[f] + w[f] * eb[f];
    hout[pos * H_ + j] = (f16)h;
  }
}

// ---------------- attention in h-space ----------------
__global__ __launch_bounds__(256) void qk_kernel(
    const float* __restrict__ qbuf, const float* __restrict__ attn_in_w,
    float* __restrict__ qk)
{
  __shared__ float qs[256];
  int b = blockIdx.x, j = threadIdx.x;
  qs[j] = qbuf[(size_t)b * 256 + j];
  __syncthreads();
#pragma unroll
  for (int h = 0; h < 4; h++) {
    float acc = 0.f;
    for (int d = 0; d < 64; d++)
      acc += qs[h * 64 + d] * attn_in_w[(size_t)(256 + h * 64 + d) * 256 + j];
    qk[((size_t)b * 4 + h) * 256 + j] = acc * 0.125f;
  }
}

__global__ __launch_bounds__(256) void attnpool_kernel(
    const f16* __restrict__ hseq, const float* __restrict__ qk,
    float* __restrict__ hbar)
{
  __shared__ __align__(16) f16 hs[T_][264];
  __shared__ float qks[4][256];
  __shared__ float ps[4][T_];
  int b = blockIdx.x, tid = threadIdx.x;
  for (int i = tid; i < T_ * 32; i += 256) {
    int row = i >> 5, cc = (i & 31) * 8;
    *(f16x8*)&hs[row][cc] = *(const f16x8*)&hseq[((size_t)b * T_ + row) * 256 + cc];
  }
  for (int i = tid; i < 1024; i += 256) qks[i >> 8][i & 255] = qk[(size_t)b * 1024 + i];
  __syncthreads();
  if (tid < T_) {
    float s[4] = {0.f, 0.f, 0.f, 0.f};
    for (int cc = 0; cc < 32; cc++) {
      f16x8 v = *(const f16x8*)&hs[tid][cc * 8];
#pragma unroll
      for (int h = 0; h < 4; h++) {
        float a = 0.f;
#pragma unroll
        for (int j = 0; j < 8; j++) a += qks[h][cc * 8 + j] * (float)v[j];
        s[h] += a;
      }
    }
#pragma unroll
    for (int h = 0; h < 4; h++) ps[h][tid] = s[h];
  }
  __syncthreads();
  {
    int w = tid >> 6, l = tid & 63;
    float a = ps[w][l], bb = ps[w][l + 64];
    float m = fmaxf(a, bb);
#pragma unroll
    for (int o = 32; o > 0; o >>= 1) m = fmaxf(m, __shfl_xor(m, o, 64));
    float e0 = __expf(a - m), e1 = __expf(bb - m);
    float se = e0 + e1;
#pragma unroll
    for (int o = 32; o > 0; o >>= 1) se += __shfl_xor(se, o, 64);
    float inv = 1.f / se;
    ps[w][l] = e0 * inv; ps[w][l + 64] = e1 * inv;
  }
  __syncthreads();
  int j = tid;
  float acc[4] = {0.f, 0.f, 0.f, 0.f};
  for (int t = 0; t < T_; t++) {
    float hv = (float)hs[t][j];
#pragma unroll
    for (int h = 0; h < 4; h++) acc[h] += ps[h][t] * hv;
  }
#pragma unroll
  for (int h = 0; h < 4; h++) hbar[((size_t)b * 4 + h) * 256 + j] = acc[h];
}

__global__ __launch_bounds__(256) void vproj_kernel(
    const float* __restrict__ hbar, const float* __restrict__ attn_in_w,
    const float* __restrict__ attn_in_b, f16* __restrict__ aob)
{
  __shared__ float hb[4][256];
  int b = blockIdx.x, tid = threadIdx.x;
  for (int i = tid; i < 1024; i += 256) hb[i >> 8][i & 255] = hbar[(size_t)b * 1024 + i];
  __syncthreads();
  int d = tid, h = d >> 6;
  const float4* wr = (const float4*)(attn_in_w + (size_t)(512 + d) * 256);
  float acc = 0.f;
  for (int cc = 0; cc < 64; cc++) {
    float4 w4 = wr[cc];
    acc += w4.x * hb[h][cc * 4] + w4.y * hb[h][cc * 4 + 1]
         + w4.z * hb[h][cc * 4 + 2] + w4.w * hb[h][cc * 4 + 3];
  }
  aob[(size_t)b * 256 + d] = (f16)(acc + attn_in_b[512 + d]);
}

// ---------------- GNN prep ----------------
__global__ __launch_bounds__(256) void deg_adjn_kernel(
    const float* __restrict__ adj, const int* __restrict__ sku,
    f16* __restrict__ adjn)
{
  int bp = blockIdx.x;
  int p = sku[bp];
  int tid = threadIdx.x;
  float s = 0.f;
  for (int j = tid; j < P_; j += 256) s += adj[(size_t)p * P_ + j];
  float tot = blk_sum(s);
  float inv = 1.f / fmaxf(tot, 1e-6f);
  for (int b = tid; b < B_; b += 256)
    adjn[(size_t)bp * B_ + b] = (f16)(adj[(size_t)p * P_ + sku[b]] * inv);
}

__global__ void transpose_kernel(const float* __restrict__ hid, f16* __restrict__ hT)
{
  int i = blockIdx.x * 256 + threadIdx.x;
  int b = i >> 8, j = i & 255;
  hT[(size_t)j * B_ + b] = (f16)hid[i];
}

__global__ __launch_bounds__(256) void gelu_ln_kernel(
    const float* __restrict__ pre, const float* __restrict__ lg,
    const float* __restrict__ lb, float* __restrict__ enr,
    f16* __restrict__ hidcat)
{
  int row = blockIdx.x, j = threadIdx.x;
  float xv = pre[row * 256 + j];
  float ge = 0.5f * xv * (1.f + erff(xv * 0.70710678118654752f));
  float mu = blk_sum(ge) * (1.f / 256.f);
  float d = ge - mu;
  float var = blk_sum(d * d) * (1.f / 256.f);
  float y = d * rsqrtf(var + 1e-5f) * lg[j] + lb[j];
  enr[row * 256 + j] = y;
  hidcat[row * 512 + 256 + j] = (f16)y;
}

__global__ __launch_bounds__(256) void final_kernel(
    const float* __restrict__ gpre, const float* __restrict__ enr,
    const float* __restrict__ hid, const float* __restrict__ outw,
    const float* __restrict__ outb, float* __restrict__ out)
{
  int b = blockIdx.x, j = threadIdx.x;
  float gt = sigf(gpre[b * 256 + j]);
  float comb = gt * enr[b * 256 + j] + (1.f - gt) * hid[b * 256 + j];
  float v = comb * outw[j];
  float s = blk_sum(v);
  if (j == 0) out[b] = s + outb[0];
}

// ---------------- one-shot weight prep ----------------
// wpk layout: elem = ((((s*4+w)*4+g)*16+k)*64+lane)*8 + j
// row = g*256 + s*64 + w*16 + (lane&15); col = k*32 + (lane>>4)*8 + j
// threads: 524288 + 3*65536 + 131072 + 2*1024 = 854016 = 3336 blocks
__global__ void prep_kernel(
    const float* Wih0, const float* Whh0, const float* Wih1, const float* Whh1,
    const float* bih0, const float* bhh0, const float* bih1, const float* bhh1,
    const float* attn_in_w, const float* attn_out_w, const float* gnn_w,
    const float* gate_w,
    f16* wpk0, f16* wpk1, f16* attninf, f16* attnoutf, f16* gnnwf, f16* gatewf,
    float* bias0, float* bias1)
{
  int idx = blockIdx.x * 256 + threadIdx.x;
  if (idx < 524288) {
    int j = idx & 7, lane = (idx >> 3) & 63, k = (idx >> 9) & 15;
    int g = (idx >> 13) & 3, w = (idx >> 15) & 3, s = (idx >> 17) & 3;
    int row = g * 256 + s * 64 + w * 16 + (lane & 15);
    int col = k * 32 + (lane >> 4) * 8 + j;
    float v0 = col < 256 ? Wih0[(size_t)row * 256 + col] : Whh0[(size_t)row * 256 + col - 256];
    float v1 = col < 256 ? Wih1[(size_t)row * 256 + col] : Whh1[(size_t)row * 256 + col - 256];
    wpk0[idx] = (f16)v0;
    wpk1[idx] = (f16)v1;
    return;
  }
  int i = idx - 524288;
  if (i < 65536) { attninf[i] = (f16)attn_in_w[i]; return; }
  i -= 65536;
  if (i < 65536) { attnoutf[i] = (f16)attn_out_w[i]; return; }
  i -= 65536;
  if (i < 65536) { gnnwf[i] = (f16)gnn_w[i]; return; }
  i -= 65536;
  if (i < 131072) { gatewf[i] = (f16)gate_w[i]; return; }
  i -= 131072;
  if (i < 1024) { bias0[i] = bih0[i] + bhh0[i]; return; }
  i -= 1024;
  if (i < 1024) { bias1[i] = bih1[i] + bhh1[i]; return; }
}

// ---------------- launch ----------------
extern "C" void kernel_launch(void* const* d_in, const int* in_sizes, int n_in,
                              void* d_out, int out_size, void* d_ws, size_t ws_size,
                              hipStream_t stream)
{
  const float* x         = (const float*)d_in[0];
  const int*   sku       = (const int*)  d_in[1];
  const float* adj       = (const float*)d_in[2];
  const float* vsn_emb_w = (const float*)d_in[3];
  const float* vsn_emb_b = (const float*)d_in[4];
  const float* vsn_sel_w = (const float*)d_in[5];
  const float* vsn_sel_b = (const float*)d_in[6];
  const float* Wih0 = (const float*)d_in[7];
  const float* Whh0 = (const float*)d_in[8];
  const float* bih0 = (const float*)d_in[9];
  const float* bhh0 = (const float*)d_in[10];
  const float* Wih1 = (const float*)d_in[11];
  const float* Whh1 = (const float*)d_in[12];
  const float* bih1 = (const float*)d_in[13];
  const float* bhh1 = (const float*)d_in[14];
  const float* attn_in_w  = (const float*)d_in[15];
  const float* attn_in_b  = (const float*)d_in[16];
  const float* attn_out_w = (const float*)d_in[17];
  const float* attn_out_b = (const float*)d_in[18];
  const float* gnn_w  = (const float*)d_in[19];
  const float* gnn_b  = (const float*)d_in[20];
  const float* ln_g   = (const float*)d_in[21];
  const float* ln_b   = (const float*)d_in[22];
  const float* gate_w = (const float*)d_in[23];
  const float* gate_b = (const float*)d_in[24];
  const float* out_w  = (const float*)d_in[25];
  const float* out_b  = (const float*)d_in[26];
  (void)in_sizes; (void)n_in; (void)out_size; (void)ws_size;

  char* wsb = (char*)d_ws;
  size_t off = 0;
  auto alloc = [&](size_t bytes) -> void* {
    void* p = wsb + off;
    off += (bytes + 255) & ~(size_t)255;
    return p;
  };
  // persistent
  f16* hA      = (f16*)alloc((size_t)B_ * T_ * H_ * 2);   // 67 MB, in-place pipeline
  f16* wpk0    = (f16*)alloc((size_t)1024 * 512 * 2);
  f16* wpk1    = (f16*)alloc((size_t)1024 * 512 * 2);
  f16* attninf = (f16*)alloc((size_t)256 * 256 * 2);
  f16* attnoutf= (f16*)alloc((size_t)256 * 256 * 2);
  f16* gnnwf   = (f16*)alloc((size_t)256 * 256 * 2);
  f16* gatewf  = (f16*)alloc((size_t)256 * 512 * 2);
  float* bias0 = (float*)alloc(1024 * 4);
  float* bias1 = (float*)alloc(1024 * 4);
  int* cnt0    = (int*)alloc(64 * 64 * 4);   // padded: 1 counter / 256B
  int* cnt1    = (int*)alloc(64 * 64 * 4);
  size_t off_tail = off;            // region below reused: wb aliases post-LSTM bufs
  float* qbuf  = (float*)alloc((size_t)B_ * 256 * 4);
  float* qk    = (float*)alloc((size_t)B_ * 4 * 256 * 4);
  float* hbar  = (float*)alloc((size_t)B_ * 4 * 256 * 4);
  f16* aob     = (f16*)alloc((size_t)B_ * 256 * 2);
  float* hidden32 = (float*)alloc((size_t)B_ * 256 * 4);
  f16* hidcat  = (f16*)alloc((size_t)B_ * 512 * 2);
  f16* hT      = (f16*)alloc((size_t)256 * B_ * 2);
  f16* adjn    = (f16*)alloc((size_t)B_ * B_ * 2);
  f16* aggf    = (f16*)alloc((size_t)B_ * 256 * 2);
  float* gnnpre= (float*)alloc((size_t)B_ * 256 * 4);
  float* enr32 = (float*)alloc((size_t)B_ * 256 * 4);
  float* gatepre=(float*)alloc((size_t)B_ * 256 * 4);
  float* wb    = (float*)(wsb + off_tail);  // 9.4 MB, dead before qbuf is written

  // zero the group counters (ws is re-poisoned 0xAA before every launch)
  hipMemsetAsync(cnt0, 0, 2 * 64 * 64 * 4, stream);

  prep_kernel<<<3336, 256, 0, stream>>>(
      Wih0, Whh0, Wih1, Whh1, bih0, bhh0, bih1, bhh1,
      attn_in_w, attn_out_w, gnn_w, gate_w,
      wpk0, wpk1, attninf, attnoutf, gnnwf, gatewf, bias0, bias1);

  // 1) VSN -> hA
  vsn_w_kernel<<<512, 256, 0, stream>>>(x, vsn_sel_w, vsn_sel_b, wb);
  vsn_h_kernel<<<1024, 256, 0, stream>>>(wb, vsn_emb_w, vsn_emb_b, hA);
  // 2) LSTM layers, register-resident weights, in place
  lstm_sync<<<256, 256, 0, stream>>>(hA, wpk0, bias0, cnt0);
  lstm_sync<<<256, 256, 0, stream>>>(hA, wpk1, bias1, cnt1);

  // 3) q at t=T-1
  dim3 gS(B_ / 128, 256 / 128);
  gemm_f16<<<gS, 256, 0, stream>>>(hA + (size_t)(T_ - 1) * 256, T_ * 256, attninf, 256,
                                   attn_in_b, nullptr, 0, qbuf, 256, B_, 256, 256);
  // 4) attention folded into h-space
  qk_kernel<<<B_, 256, 0, stream>>>(qbuf, attn_in_w, qk);
  attnpool_kernel<<<B_, 256, 0, stream>>>(hA, qk, hbar);
  vproj_kernel<<<B_, 256, 0, stream>>>(hbar, attn_in_w, attn_in_b, aob);
  // 5) hidden
  gemm_f16<<<gS, 256, 0, stream>>>(aob, 256, attnoutf, 256, attn_out_b,
                                   hidcat, 512, hidden32, 256, B_, 256, 256);
  // 6) GNN
  deg_adjn_kernel<<<B_, 256, 0, stream>>>(adj, sku, adjn);
  transpose_kernel<<<B_, 256, 0, stream>>>(hidden32, hT);
  gemm_f16<<<gS, 256, 0, stream>>>(adjn, 1024, hT, 1024, nullptr,
                                   aggf, 256, nullptr, 0, B_, 256, 1024);
  gemm_f16<<<gS, 256, 0, stream>>>(aggf, 256, gnnwf, 256, gnn_b,
                                   nullptr, 0, gnnpre, 256, B_, 256, 256);
  gelu_ln_kernel<<<B_, 256, 0, stream>>>(gnnpre, ln_g, ln_b, enr32, hidcat);
  // 7) gate + output
  gemm_f16<<<gS, 256, 0, stream>>>(hidcat, 512, gatewf, 512, gate_b,
                                   nullptr, 0, gatepre, 256, B_, 256, 512);
  final_kernel<<<B_, 256, 0, stream>>>(gatepre, enr32, hidden32, out_w, out_b, (float*)d_out);
}